// Round 11
// baseline (328.640 us; speedup 1.0000x reference)
//
#include <hip/hip_runtime.h>

#define DD 256
#define HWN 1024
#define NN 32768
#define KK 1024
#define MARGIN 1e-4f
#define FLAGBIT (1 << 30)

// f32-element offsets into d_out (out_size = 16809984 floats):
#define ZQ_OFF   0          // z_q   [32,256,32,32]
#define IDX_OFF  8388608    // idx   [32768]
#define LOSS_OFF 8421376    // loss  [32,32,32,256] (NHWC)

// ws layout (MFMA path needs WS_NEED bytes; else fp32 fallback):
// [0, 4096)            float e2[1024]
// [4096, 135168)       float z2[32768]
// [135168, 266240)     int   bestIdx[32768]
// [266240, 3411968)    float part[32768][8][3]
// [3411968, 3936256)   ushort Eh[1024][256]
// [3936256, 4460544)   ushort El[1024][256]
// [4460544, 21237760)  ushort Zh[32768][256]
// [21237760, 38014976) ushort Zl[32768][256]
// [38014976, 38015040) int flagCount
// [38015040, 38146112) int flagList[32768]
#define WS_NEED 38146112

typedef __attribute__((ext_vector_type(8))) short bf16x8;
typedef __attribute__((ext_vector_type(4))) float f32x4;

__device__ __forceinline__ ushort f2b_rne(float x) {
    union { float f; unsigned u; } v; v.f = x;
    unsigned r = v.u + 0x7fffu + ((v.u >> 16) & 1u);
    return (ushort)(r >> 16);
}
__device__ __forceinline__ float b2f(ushort u) {
    union { unsigned u_; float f; } v; v.u_ = (unsigned)u << 16; return v.f;
}

// ---------------- e2[k]: numpy-exact f32 codebook norms ----------------
__global__ __launch_bounds__(64) void k_e2(const float* __restrict__ E,
                                           float* __restrict__ e2) {
    int k = (blockIdx.x << 6) + threadIdx.x;
    const float* row = E + (size_t)k * DD;
    float half[2];
#pragma unroll
    for (int h = 0; h < 2; ++h) {
        const float* a = row + (h << 7);
        float r[8];
#pragma unroll
        for (int j = 0; j < 8; ++j) r[j] = __fmul_rn(a[j], a[j]);
        for (int i = 8; i < 128; i += 8) {
#pragma unroll
            for (int j = 0; j < 8; ++j) {
                float x = a[i + j];
                r[j] = __fadd_rn(r[j], __fmul_rn(x, x));
            }
        }
        half[h] = __fadd_rn(__fadd_rn(__fadd_rn(r[0], r[1]), __fadd_rn(r[2], r[3])),
                            __fadd_rn(__fadd_rn(r[4], r[5]), __fadd_rn(r[6], r[7])));
    }
    e2[k] = __fadd_rn(half[0], half[1]);
}

// -- fused: Z transpose tile -> Zh/Zl bf16 [n][d] + numpy-exact z2 --
__global__ __launch_bounds__(256) void k_prepZ2(const float* __restrict__ Z,
                                                ushort* __restrict__ Zh,
                                                ushort* __restrict__ Zl,
                                                float* __restrict__ z2) {
    __shared__ float zc[16][257];      // 16448 B
    const int g = blockIdx.x;          // 2048 blocks: 16 rows each
    const int b = g >> 6;
    const int hw0 = (g & 63) << 4;
    const int th = threadIdx.x;
    const int n0 = (b << 10) + hw0;

#pragma unroll
    for (int j = 0; j < 16; ++j) {
        int li = (j << 8) + th;        // 0..4095
        int d = li >> 4;
        int hl = li & 15;
        zc[hl][d] = Z[(size_t)((b << 8) + d) * HWN + hw0 + hl];
    }
    __syncthreads();

    // bf16 high+low split (RNE), [n][d] layout, 32B/thread contiguous per array
    {
        int r = th >> 4, c = th & 15;
        ushort hs[16], ls[16];
#pragma unroll
        for (int i = 0; i < 16; ++i) {
            float z = zc[r][(c << 4) + i];
            ushort h = f2b_rne(z);
            hs[i] = h;
            ls[i] = f2b_rne(z - b2f(h));
        }
        size_t addr = (size_t)(n0 + r) * DD + (c << 4);
        *reinterpret_cast<bf16x8*>(&Zh[addr]) = *reinterpret_cast<bf16x8*>(&hs[0]);
        *reinterpret_cast<bf16x8*>(&Zh[addr + 8]) = *reinterpret_cast<bf16x8*>(&hs[8]);
        *reinterpret_cast<bf16x8*>(&Zl[addr]) = *reinterpret_cast<bf16x8*>(&ls[0]);
        *reinterpret_cast<bf16x8*>(&Zl[addr + 8]) = *reinterpret_cast<bf16x8*>(&ls[8]);
    }

    // z2: numpy pairwise (identical op order to the validated k_z2)
    if (th < 16) {
        const float* rowp = &zc[th][0];
        float half[2];
#pragma unroll
        for (int h = 0; h < 2; ++h) {
            const float* a = rowp + (h << 7);
            float r[8];
#pragma unroll
            for (int j = 0; j < 8; ++j) r[j] = __fmul_rn(a[j], a[j]);
            for (int i = 8; i < 128; i += 8) {
#pragma unroll
                for (int j = 0; j < 8; ++j) {
                    float x = a[i + j];
                    r[j] = __fadd_rn(r[j], __fmul_rn(x, x));
                }
            }
            half[h] = __fadd_rn(__fadd_rn(__fadd_rn(r[0], r[1]), __fadd_rn(r[2], r[3])),
                                __fadd_rn(__fadd_rn(r[4], r[5]), __fadd_rn(r[6], r[7])));
        }
        z2[n0 + th] = __fadd_rn(half[0], half[1]);
    }
}

// ---------------- z2 standalone (fallback path only) ----------------
__global__ __launch_bounds__(256) void k_z2(const float* __restrict__ Z,
                                            float* __restrict__ z2) {
    int n = (blockIdx.x << 8) + threadIdx.x;
    int b = n >> 10, hw = n & 1023;
    const float* base = Z + (size_t)(b << 8) * HWN + hw;
    float half[2];
#pragma unroll
    for (int h = 0; h < 2; ++h) {
        const float* a = base + (size_t)(h << 7) * HWN;
        float r[8];
#pragma unroll
        for (int j = 0; j < 8; ++j) {
            float x = a[(size_t)j * HWN];
            r[j] = __fmul_rn(x, x);
        }
        for (int i = 8; i < 128; i += 8) {
#pragma unroll
            for (int j = 0; j < 8; ++j) {
                float x = a[(size_t)(i + j) * HWN];
                r[j] = __fadd_rn(r[j], __fmul_rn(x, x));
            }
        }
        half[h] = __fadd_rn(__fadd_rn(__fadd_rn(r[0], r[1]), __fadd_rn(r[2], r[3])),
                            __fadd_rn(__fadd_rn(r[4], r[5]), __fadd_rn(r[6], r[7])));
    }
    z2[n] = __fadd_rn(half[0], half[1]);
}

// ---------------- prep: E -> Eh/El bf16 (+ zero flag counter) ----------------
__global__ __launch_bounds__(256) void k_prepE(const float* __restrict__ E,
                                               ushort* __restrict__ Eh,
                                               ushort* __restrict__ El,
                                               int* __restrict__ flagCount) {
    if (blockIdx.x == 0 && threadIdx.x == 0) *flagCount = 0;
    int i4 = (blockIdx.x << 8) + threadIdx.x;        // 0..65535 float4s
    float4 v = *reinterpret_cast<const float4*>(&E[(size_t)i4 << 2]);
    ushort4 h, l;
    h.x = f2b_rne(v.x); l.x = f2b_rne(v.x - b2f(h.x));
    h.y = f2b_rne(v.y); l.y = f2b_rne(v.y - b2f(h.y));
    h.z = f2b_rne(v.z); l.z = f2b_rne(v.z - b2f(h.z));
    h.w = f2b_rne(v.w); l.w = f2b_rne(v.w - b2f(h.w));
    *reinterpret_cast<ushort4*>(&Eh[(size_t)i4 << 2]) = h;
    *reinterpret_cast<ushort4*>(&El[(size_t)i4 << 2]) = l;
}

// --- MFMA distance pass, LDS-free: frags direct from L2, XCD-aware mapping ---
// split-bf16: dot = zh*eh + zh*el + zl*eh (err ~1e-7 << MARGIN)
__global__ __launch_bounds__(256) void k_dist_mfma(const ushort* __restrict__ Zh,
                                                   const ushort* __restrict__ Zl,
                                                   const ushort* __restrict__ Eh,
                                                   const ushort* __restrict__ El,
                                                   const float* __restrict__ e2,
                                                   float* __restrict__ part) {
    __shared__ float red[128][2][3];   // 3 KB only

    const int B = blockIdx.x;          // 2048 blocks
    // XCD-aware: xcd = B&7; its 256 blocks sweep rb contiguously, the 8 cb
    // blocks of each rb adjacent in dispatch order -> Zh/Zl L2-resident per XCD.
    const int xcd = B & 7;
    const int j = B >> 3;              // 0..255
    const int cb = j & 7;
    const int rbl = j >> 3;            // 0..31
    const int rb = (xcd << 5) + rbl;
    const int n0 = rb << 7, c0 = cb << 7;
    const int th = threadIdx.x;
    const int wid = th >> 6, lane = th & 63;
    const int wr = wid >> 1, wc = wid & 1;
    const int fr = lane & 15, kg = (lane >> 4) << 3;

    f32x4 acc[4][4];
#pragma unroll
    for (int i = 0; i < 4; ++i)
#pragma unroll
        for (int jj = 0; jj < 4; ++jj) acc[i][jj] = (f32x4){0.f, 0.f, 0.f, 0.f};

    const size_t zrow0 = (size_t)(n0 + (wr << 6) + fr) * DD + kg;
    const size_t erow0 = (size_t)(c0 + (wc << 6) + fr) * DD + kg;

#pragma unroll 2
    for (int kc = 0; kc < 8; ++kc) {
        const size_t ko = (size_t)(kc << 5);
        bf16x8 za[4], zb[4], ea[4], eb[4];
#pragma unroll
        for (int mi = 0; mi < 4; ++mi) {
            size_t a = zrow0 + (size_t)(mi << 4) * DD + ko;
            za[mi] = *reinterpret_cast<const bf16x8*>(&Zh[a]);
            zb[mi] = *reinterpret_cast<const bf16x8*>(&Zl[a]);
        }
#pragma unroll
        for (int ni = 0; ni < 4; ++ni) {
            size_t a = erow0 + (size_t)(ni << 4) * DD + ko;
            ea[ni] = *reinterpret_cast<const bf16x8*>(&Eh[a]);
            eb[ni] = *reinterpret_cast<const bf16x8*>(&El[a]);
        }
#pragma unroll
        for (int mi = 0; mi < 4; ++mi)
#pragma unroll
            for (int ni = 0; ni < 4; ++ni) {
                acc[mi][ni] = __builtin_amdgcn_mfma_f32_16x16x32_bf16(za[mi], ea[ni], acc[mi][ni], 0, 0, 0);
                acc[mi][ni] = __builtin_amdgcn_mfma_f32_16x16x32_bf16(za[mi], eb[ni], acc[mi][ni], 0, 0, 0);
                acc[mi][ni] = __builtin_amdgcn_mfma_f32_16x16x32_bf16(zb[mi], ea[ni], acc[mi][ni], 0, 0, 0);
            }
    }

    float e2v[4];
#pragma unroll
    for (int ni = 0; ni < 4; ++ni) e2v[ni] = e2[c0 + (wc << 6) + (ni << 4) + fr];

    const int rg = lane >> 4;
#pragma unroll
    for (int mi = 0; mi < 4; ++mi) {
#pragma unroll
        for (int jj = 0; jj < 4; ++jj) {
            float m1 = __builtin_inff(), m2 = __builtin_inff(), bi = 3.4e38f;
#pragma unroll
            for (int ni = 0; ni < 4; ++ni) {
                float s = fmaf(-2.f, acc[mi][ni][jj], e2v[ni]);
                float c = (float)(c0 + (wc << 6) + (ni << 4) + fr);
                if (s < m1)      { m2 = m1; m1 = s; bi = c; }
                else if (s < m2) { m2 = s; }
            }
#pragma unroll
            for (int m = 1; m <= 8; m <<= 1) {
                float om1 = __shfl_xor(m1, m);
                float om2 = __shfl_xor(m2, m);
                float obi = __shfl_xor(bi, m);
                if (om1 < m1)       { m2 = fminf(m1, om2); m1 = om1; bi = obi; }
                else if (om1 == m1) { bi = fminf(bi, obi); m2 = m1; }
                else                { m2 = fminf(m2, om1); }
            }
            if (fr == 0) {
                int row = (wr << 6) + (mi << 4) + (rg << 2) + jj;
                red[row][wc][0] = m1; red[row][wc][1] = m2; red[row][wc][2] = bi;
            }
        }
    }
    __syncthreads();
    if (th < 128) {
        float M1 = red[th][0][0], M2 = red[th][0][1], I = red[th][0][2];
        float v1 = red[th][1][0], v2 = red[th][1][1], vi = red[th][1][2];
        if (v1 < M1)       { M2 = fminf(M1, v2); M1 = v1; I = vi; }
        else if (v1 == M1) { I = fminf(I, vi); M2 = M1; }
        else               { M2 = fminf(M2, v1); }
        size_t p = ((size_t)(n0 + th) * 8 + cb) * 3;
        part[p] = M1; part[p + 1] = M2; part[p + 2] = I;
    }
}

// ------- combine 8 code-slices -> bestIdx + compacted near-tie list -------
__global__ __launch_bounds__(256) void k_combine(const float* __restrict__ part,
                                                 int* __restrict__ bestIdx,
                                                 int* __restrict__ flagList,
                                                 int* __restrict__ flagCount) {
    int n = (blockIdx.x << 8) + threadIdx.x;
    const float* p = part + (size_t)n * 24;
    float M1 = __builtin_inff(), M2 = __builtin_inff(), I = 3.4e38f;
    for (int c = 0; c < 8; ++c) {
        float v1 = p[c * 3], v2 = p[c * 3 + 1], vi = p[c * 3 + 2];
        if (v1 < M1)       { M2 = fminf(M1, v2); M1 = v1; I = vi; }
        else if (v1 == M1) { I = fminf(I, vi); M2 = M1; }
        else               { M2 = fminf(M2, v1); }
    }
    bestIdx[n] = (int)I;
    if (M2 - M1 < MARGIN) {
        int pos = atomicAdd(flagCount, 1);
        flagList[pos] = n;
    }
}

// ---- block-parallel np-f32-grid re-argmin: 4 rows x 16 codes x 4 d-slices ----
__global__ __launch_bounds__(256) void k_refine2(const float* __restrict__ Z,
                                                 const float* __restrict__ E,
                                                 const float* __restrict__ e2,
                                                 const float* __restrict__ z2,
                                                 int* __restrict__ bestIdx,
                                                 const int* __restrict__ flagList,
                                                 const int* __restrict__ flagCount) {
    __shared__ float ec[16][257];      // 16448 B: 16-code E chunk
    __shared__ float zr4[4][257];      //  4112 B: 4 z rows
    __shared__ double pd[16][4][4];    //  2048 B: partial dots (code, row, slice)
    __shared__ int rown[4];
    __shared__ float rz2[4];

    const int th = threadIdx.x;
    const int cl = th & 15;            // code-in-chunk
    const int rr = (th >> 4) & 3;      // row
    const int sl = th >> 6;            // d-slice (64 d each)
    const int cnt = *flagCount;

    for (int grp = blockIdx.x; grp * 4 < cnt; grp += (int)gridDim.x) {
        __syncthreads();               // protect rown/zr4/rz2 vs previous group
        if (th < 4) {
            int i = grp * 4 + th;
            if (i >= cnt) i = cnt - 1; // duplicate row: identical result, benign
            int n = flagList[i];
            rown[th] = n;
            rz2[th] = z2[n];
        }
        __syncthreads();
        for (int li = th; li < 1024; li += 256) {
            int r = li >> 8, d = li & 255;
            int n = rown[r];
            zr4[r][d] = Z[(size_t)(((n >> 10) << 8) + d) * HWN + (n & 1023)];
        }
        float gbest = __builtin_inff();
        int bi = 0;
        __syncthreads();

        for (int ch = 0; ch < 64; ++ch) {
            // stage 16 codes (coalesced float4); safe: prev compute done at barrier-2
#pragma unroll
            for (int j = 0; j < 4; ++j) {
                int li4 = (j << 8) + th;
                int c = li4 >> 6, d4 = (li4 & 63) << 2;
                *reinterpret_cast<float4*>(&ec[c][d4]) =
                    *reinterpret_cast<const float4*>(&E[(size_t)((ch << 4) + c) * DD + d4]);
            }
            // consume pd of chunk ch-1 (written before barrier-2 of prev iter)
            if (sl == 0 && ch > 0) {
                double dot = (pd[cl][rr][0] + pd[cl][rr][1]) + (pd[cl][rr][2] + pd[cl][rr][3]);
                int k = ((ch - 1) << 4) + cl;
                float c = (float)dot;
                float t2 = __fmul_rn(2.0f, c);
                float gg = __fsub_rn(__fadd_rn(rz2[rr], e2[k]), t2);
                if (gg < gbest) { gbest = gg; bi = k; }
            }
            __syncthreads();           // barrier-1: ec ready; pd(ch-1) consumed
            {
                const int db = sl << 6;
                double s0 = 0, s1 = 0, s2 = 0, s3 = 0;
#pragma unroll
                for (int d = 0; d < 64; d += 4) {
                    s0 += (double)ec[cl][db + d]     * zr4[rr][db + d];
                    s1 += (double)ec[cl][db + d + 1] * zr4[rr][db + d + 1];
                    s2 += (double)ec[cl][db + d + 2] * zr4[rr][db + d + 2];
                    s3 += (double)ec[cl][db + d + 3] * zr4[rr][db + d + 3];
                }
                pd[cl][rr][sl] = (s0 + s1) + (s2 + s3);
            }
            __syncthreads();           // barrier-2: pd ready; ec reads done
        }
        if (sl == 0) {
            // last chunk
            {
                double dot = (pd[cl][rr][0] + pd[cl][rr][1]) + (pd[cl][rr][2] + pd[cl][rr][3]);
                int k = (63 << 4) + cl;
                float c = (float)dot;
                float t2 = __fmul_rn(2.0f, c);
                float gg = __fsub_rn(__fadd_rn(rz2[rr], e2[k]), t2);
                if (gg < gbest) { gbest = gg; bi = k; }
            }
            // reduce across the 16 code-lanes of each row
#pragma unroll
            for (int m = 1; m <= 8; m <<= 1) {
                float og = __shfl_xor(gbest, m);
                int oi = __shfl_xor(bi, m);
                if (og < gbest || (og == gbest && oi < bi)) { gbest = og; bi = oi; }
            }
            if (cl == 0) bestIdx[rown[rr]] = bi;
        }
    }
}

// ======== fp32 fallback distance pass (used if ws too small) ========
#define UPD(m1, m2, i1, s, k)                            \
    do {                                                 \
        if ((s) < (m1)) { m2 = m1; m1 = (s); i1 = (k); } \
        else if ((s) < (m2)) { m2 = (s); }               \
    } while (0)

#define FMAJ(j, EV, C)                                   \
    acc[0][j] = fmaf(z4.x, EV.C, acc[0][j]);             \
    acc[1][j] = fmaf(z4.y, EV.C, acc[1][j]);             \
    acc[2][j] = fmaf(z4.z, EV.C, acc[2][j]);             \
    acc[3][j] = fmaf(z4.w, EV.C, acc[3][j]);

#define UROUND(u, C)                                                          \
    {                                                                         \
        float4 z4 = *reinterpret_cast<const float4*>(&zs[dq + u][ty4]);       \
        FMAJ(0, e0, C) FMAJ(1, e1, C) FMAJ(2, e2v, C) FMAJ(3, e3, C)          \
        FMAJ(4, e4, C) FMAJ(5, e5, C) FMAJ(6, e6, C) FMAJ(7, e7, C)           \
    }

__global__ __launch_bounds__(256, 3) void k_dist_f32(const float* __restrict__ Z,
                                                     const float* __restrict__ E,
                                                     const float* __restrict__ e2,
                                                     int* __restrict__ bestIdx) {
    __shared__ float zs[64][68];
    __shared__ float es[128][68];
    const int th = threadIdx.x;
    const int n0 = blockIdx.x << 6;
    const int b = n0 >> 10;
    const int hw0 = n0 & 1023;
    const int tx = th & 15;
    const int ty = th >> 4;
    const int ty4 = ty << 2;
    float m1[4], m2[4];
    int idx[4];
#pragma unroll
    for (int i = 0; i < 4; ++i) { m1[i] = __builtin_inff(); m2[i] = __builtin_inff(); idx[i] = 0; }
    for (int ct = 0; ct < 8; ++ct) {
        float acc[4][8];
#pragma unroll
        for (int i = 0; i < 4; ++i)
#pragma unroll
            for (int j = 0; j < 8; ++j) acc[i][j] = 0.f;
        for (int dc = 0; dc < 4; ++dc) {
            __syncthreads();
#pragma unroll
            for (int j = 0; j < 4; ++j) {
                int i4 = (j << 8) + th;
                int dd = i4 >> 4;
                int rr = (i4 & 15) << 2;
                *reinterpret_cast<float4*>(&zs[dd][rr]) =
                    *reinterpret_cast<const float4*>(
                        &Z[(size_t)((b << 8) + (dc << 6) + dd) * HWN + hw0 + rr]);
            }
#pragma unroll
            for (int j = 0; j < 8; ++j) {
                int i4 = (j << 8) + th;
                int c = i4 >> 4;
                int d4 = (i4 & 15) << 2;
                *reinterpret_cast<float4*>(&es[c][d4]) =
                    *reinterpret_cast<const float4*>(
                        &E[(size_t)((ct << 7) + c) * DD + (dc << 6) + d4]);
            }
            __syncthreads();
#pragma unroll
            for (int dq = 0; dq < 64; dq += 4) {
                float4 e0 = *reinterpret_cast<const float4*>(&es[tx][dq]);
                float4 e1 = *reinterpret_cast<const float4*>(&es[tx + 16][dq]);
                float4 e2v = *reinterpret_cast<const float4*>(&es[tx + 32][dq]);
                float4 e3 = *reinterpret_cast<const float4*>(&es[tx + 48][dq]);
                float4 e4 = *reinterpret_cast<const float4*>(&es[tx + 64][dq]);
                float4 e5 = *reinterpret_cast<const float4*>(&es[tx + 80][dq]);
                float4 e6 = *reinterpret_cast<const float4*>(&es[tx + 96][dq]);
                float4 e7 = *reinterpret_cast<const float4*>(&es[tx + 112][dq]);
                UROUND(0, x)
                UROUND(1, y)
                UROUND(2, z)
                UROUND(3, w)
            }
        }
#pragma unroll
        for (int j = 0; j < 8; ++j) {
            int c = (ct << 7) + tx + (j << 4);
            float en = e2[c];
#pragma unroll
            for (int i = 0; i < 4; ++i) {
                float s = fmaf(-2.f, acc[i][j], en);
                UPD(m1[i], m2[i], idx[i], s, c);
            }
        }
    }
    __syncthreads();
    float* red = &es[0][0];
#pragma unroll
    for (int i = 0; i < 4; ++i) {
        int r = ty4 + i;
        int base = ((r << 4) + tx) * 3;
        red[base] = m1[i]; red[base + 1] = m2[i]; red[base + 2] = (float)idx[i];
    }
    __syncthreads();
    if (th < 64) {
        float M1 = __builtin_inff(), M2 = __builtin_inff(), I = 3.4e38f;
        for (int t = 0; t < 16; ++t) {
            int base = ((th << 4) + t) * 3;
            float v1 = red[base], v2 = red[base + 1], vi = red[base + 2];
            if (v1 < M1)       { M2 = fminf(M1, v2); M1 = v1; I = vi; }
            else if (v1 == M1) { I = fminf(I, vi); M2 = fminf(M2, v1); M2 = fminf(M2, v2); }
            else               { M2 = fminf(M2, v1); }
        }
        int id = (int)I;
        bestIdx[n0 + th] = (M2 - M1 < MARGIN) ? (id | FLAGBIT) : id;
    }
}

// -------- fallback-path refine (FLAGBIT scan, unchanged semantics) --------
__global__ __launch_bounds__(64) void k_refine(const float* __restrict__ Z,
                                               const float* __restrict__ E,
                                               const float* __restrict__ e2,
                                               const float* __restrict__ z2,
                                               int* __restrict__ bestIdx) {
    __shared__ float zr[DD];
    const int l = threadIdx.x;
    for (int i = 0; i < 16; ++i) {
        int n = (blockIdx.x << 4) + i;
        if (!(bestIdx[n] & FLAGBIT)) continue;
        int b = n >> 10, hw = n & 1023;
        __syncthreads();
#pragma unroll
        for (int j = 0; j < 4; ++j)
            zr[(l << 2) + j] = Z[(size_t)((b << 8) + (l << 2) + j) * HWN + hw];
        __syncthreads();
        const float z2v = z2[n];
        float gbest = __builtin_inff();
        int bi = KK;
        for (int kk = 0; kk < 16; ++kk) {
            int k = (kk << 6) + l;
            double dot = 0.0;
            for (int d = 0; d < DD; d += 4) {
                float4 e4 = *reinterpret_cast<const float4*>(&E[(size_t)k * DD + d]);
                dot += (double)e4.x * zr[d]     + (double)e4.y * zr[d + 1]
                     + (double)e4.z * zr[d + 2] + (double)e4.w * zr[d + 3];
            }
            float c = (float)dot;
            float t = __fmul_rn(2.0f, c);
            float gg = __fsub_rn(__fadd_rn(z2v, e2[k]), t);
            if (gg < gbest) { gbest = gg; bi = k; }
        }
#pragma unroll
        for (int off = 32; off > 0; off >>= 1) {
            float og = __shfl_down(gbest, off);
            int oi = __shfl_down(bi, off);
            if (og < gbest || (og == gbest && oi < bi)) { gbest = og; bi = oi; }
        }
        if (l == 0) bestIdx[n] = bi;
    }
}

// -------- outputs: idx, loss (NHWC), z_q (NCHW) --------
__global__ __launch_bounds__(256) void k_out(const float* __restrict__ Z,
                                             const float* __restrict__ E,
                                             const int* __restrict__ bestIdx,
                                             float* __restrict__ out) {
    __shared__ float zc[64][68];
    __shared__ int idxs[64];
    const int th = threadIdx.x;
    const int n0 = blockIdx.x << 6;
    const int b = n0 >> 10;
    const int hw0 = n0 & 1023;

    if (th < 64) {
        int id = bestIdx[n0 + th] & 1023;
        idxs[th] = id;
        out[IDX_OFF + n0 + th] = (float)id;
    }
    __syncthreads();

    for (int dc = 0; dc < 4; ++dc) {
        __syncthreads();
#pragma unroll
        for (int j = 0; j < 16; ++j) {
            int li = (j << 8) + th;
            int dd = li >> 6;
            int r = li & 63;
            zc[r][dd] = Z[(size_t)((b << 8) + (dc << 6) + dd) * HWN + hw0 + r];
        }
        __syncthreads();
#pragma unroll
        for (int j = 0; j < 4; ++j) {
            int i4 = (j << 8) + th;
            int r = i4 >> 4;
            int f = (i4 & 15) << 2;
            float4 e4 = *reinterpret_cast<const float4*>(
                &E[(size_t)idxs[r] * DD + (dc << 6) + f]);
            float4 z4 = *reinterpret_cast<const float4*>(&zc[r][f]);
            float4 o;
            o.x = (e4.x - z4.x) * (e4.x - z4.x);
            o.y = (e4.y - z4.y) * (e4.y - z4.y);
            o.z = (e4.z - z4.z) * (e4.z - z4.z);
            o.w = (e4.w - z4.w) * (e4.w - z4.w);
            *reinterpret_cast<float4*>(
                &out[LOSS_OFF + (size_t)(n0 + r) * DD + (dc << 6) + f]) = o;
        }
#pragma unroll
        for (int j = 0; j < 16; ++j) {
            int li = (j << 8) + th;
            int dd = li >> 6;
            int r = li & 63;
            out[ZQ_OFF + (size_t)((b << 8) + (dc << 6) + dd) * HWN + hw0 + r] =
                E[(size_t)idxs[r] * DD + (dc << 6) + dd];
        }
    }
}

extern "C" void kernel_launch(void* const* d_in, const int* in_sizes, int n_in,
                              void* d_out, int out_size, void* d_ws, size_t ws_size,
                              hipStream_t stream) {
    const float* Z = (const float*)d_in[0];           // [32,256,32,32] f32
    const float* E = (const float*)d_in[1];           // [1024,256] f32
    float* out = (float*)d_out;
    char* ws = (char*)d_ws;
    float* e2 = (float*)ws;
    float* z2 = (float*)(ws + 4096);
    int* bestIdx = (int*)(ws + 135168);

    k_e2<<<KK / 64, 64, 0, stream>>>(E, e2);

    if (ws_size >= WS_NEED) {
        float* part = (float*)(ws + 266240);
        ushort* Eh = (ushort*)(ws + 3411968);
        ushort* El = (ushort*)(ws + 3936256);
        ushort* Zh = (ushort*)(ws + 4460544);
        ushort* Zl = (ushort*)(ws + 21237760);
        int* flagCount = (int*)(ws + 38014976);
        int* flagList = (int*)(ws + 38015040);
        k_prepE<<<256, 256, 0, stream>>>(E, Eh, El, flagCount);
        k_prepZ2<<<2048, 256, 0, stream>>>(Z, Zh, Zl, z2);
        k_dist_mfma<<<2048, 256, 0, stream>>>(Zh, Zl, Eh, El, e2, part);
        k_combine<<<NN / 256, 256, 0, stream>>>(part, bestIdx, flagList, flagCount);
        k_refine2<<<512, 256, 0, stream>>>(Z, E, e2, z2, bestIdx, flagList, flagCount);
    } else {
        k_z2<<<NN / 256, 256, 0, stream>>>(Z, z2);
        k_dist_f32<<<NN / 64, 256, 0, stream>>>(Z, E, e2, bestIdx);
        k_refine<<<NN / 16, 64, 0, stream>>>(Z, E, e2, z2, bestIdx);
    }

    k_out<<<NN / 64, 256, 0, stream>>>(Z, E, bestIdx, out);
}

// Round 12
// 255.510 us; speedup vs baseline: 1.2862x; 1.2862x over previous
//
#include <hip/hip_runtime.h>

#define DD 256
#define HWN 1024
#define NN 32768
#define KK 1024
#define MARGIN 1e-4f
#define FLAGBIT (1 << 30)

// f32-element offsets into d_out (out_size = 16809984 floats):
#define ZQ_OFF   0          // z_q   [32,256,32,32]
#define IDX_OFF  8388608    // idx   [32768]
#define LOSS_OFF 8421376    // loss  [32,32,32,256] (NHWC)

// ws layout (MFMA path needs WS_NEED bytes; else fp32 fallback):
// [0, 4096)            float e2[1024]
// [4096, 135168)       float z2[32768]
// [135168, 266240)     int   bestIdx[32768]
// [266240, 3411968)    float part[32768][8][3]
// [3411968, 3936256)   ushort Eh[1024][256]   (f16 of 1024*E)
// [3936256, 4460544)   ushort El[1024][256]   (f16 residual of 1024*E)
// [4460544, 21237760)  ushort Zh[32768][256]  (f16 of Z, [n][d])
// [21237760, 38014976) (unused)
// [38014976, 38015040) int flagCount
// [38015040, 38146112) int flagList[32768]
#define WS_NEED 38146112

typedef __attribute__((ext_vector_type(8))) _Float16 f16x8;
typedef __attribute__((ext_vector_type(4))) float f32x4;

__device__ __forceinline__ ushort f2h(float x) {
    _Float16 h = (_Float16)x;                  // RNE
    return *reinterpret_cast<ushort*>(&h);
}
__device__ __forceinline__ float h2f(ushort u) {
    _Float16 h = *reinterpret_cast<_Float16*>(&u);
    return (float)h;
}

// ---------------- e2[k]: numpy-exact f32 codebook norms ----------------
__global__ __launch_bounds__(64) void k_e2(const float* __restrict__ E,
                                           float* __restrict__ e2) {
    int k = (blockIdx.x << 6) + threadIdx.x;
    const float* row = E + (size_t)k * DD;
    float half_[2];
#pragma unroll
    for (int h = 0; h < 2; ++h) {
        const float* a = row + (h << 7);
        float r[8];
#pragma unroll
        for (int j = 0; j < 8; ++j) r[j] = __fmul_rn(a[j], a[j]);
        for (int i = 8; i < 128; i += 8) {
#pragma unroll
            for (int j = 0; j < 8; ++j) {
                float x = a[i + j];
                r[j] = __fadd_rn(r[j], __fmul_rn(x, x));
            }
        }
        half_[h] = __fadd_rn(__fadd_rn(__fadd_rn(r[0], r[1]), __fadd_rn(r[2], r[3])),
                             __fadd_rn(__fadd_rn(r[4], r[5]), __fadd_rn(r[6], r[7])));
    }
    e2[k] = __fadd_rn(half_[0], half_[1]);
}

// -- fused: Z transpose tile -> Zh f16 [n][d] + numpy-exact z2 --
__global__ __launch_bounds__(256) void k_prepZ2(const float* __restrict__ Z,
                                                ushort* __restrict__ Zh,
                                                float* __restrict__ z2) {
    __shared__ float zc[16][257];      // 16448 B
    const int g = blockIdx.x;          // 2048 blocks: 16 rows each
    const int b = g >> 6;
    const int hw0 = (g & 63) << 4;
    const int th = threadIdx.x;
    const int n0 = (b << 10) + hw0;

#pragma unroll
    for (int j = 0; j < 16; ++j) {
        int li = (j << 8) + th;        // 0..4095
        int d = li >> 4;
        int hl = li & 15;
        zc[hl][d] = Z[(size_t)((b << 8) + d) * HWN + hw0 + hl];
    }
    __syncthreads();

    // f16 (RNE), [n][d] layout, 32B/thread contiguous
    {
        int r = th >> 4, c = th & 15;
        ushort hs[16];
#pragma unroll
        for (int i = 0; i < 16; ++i) hs[i] = f2h(zc[r][(c << 4) + i]);
        size_t addr = (size_t)(n0 + r) * DD + (c << 4);
        *reinterpret_cast<f16x8*>(&Zh[addr]) = *reinterpret_cast<f16x8*>(&hs[0]);
        *reinterpret_cast<f16x8*>(&Zh[addr + 8]) = *reinterpret_cast<f16x8*>(&hs[8]);
    }

    // z2: numpy pairwise (identical op order to the validated k_z2)
    if (th < 16) {
        const float* rowp = &zc[th][0];
        float half_[2];
#pragma unroll
        for (int h = 0; h < 2; ++h) {
            const float* a = rowp + (h << 7);
            float r[8];
#pragma unroll
            for (int j = 0; j < 8; ++j) r[j] = __fmul_rn(a[j], a[j]);
            for (int i = 8; i < 128; i += 8) {
#pragma unroll
                for (int j = 0; j < 8; ++j) {
                    float x = a[i + j];
                    r[j] = __fadd_rn(r[j], __fmul_rn(x, x));
                }
            }
            half_[h] = __fadd_rn(__fadd_rn(__fadd_rn(r[0], r[1]), __fadd_rn(r[2], r[3])),
                                 __fadd_rn(__fadd_rn(r[4], r[5]), __fadd_rn(r[6], r[7])));
        }
        z2[n0 + th] = __fadd_rn(half_[0], half_[1]);
    }
}

// ---------------- z2 standalone (fallback path only) ----------------
__global__ __launch_bounds__(256) void k_z2(const float* __restrict__ Z,
                                            float* __restrict__ z2) {
    int n = (blockIdx.x << 8) + threadIdx.x;
    int b = n >> 10, hw = n & 1023;
    const float* base = Z + (size_t)(b << 8) * HWN + hw;
    float half_[2];
#pragma unroll
    for (int h = 0; h < 2; ++h) {
        const float* a = base + (size_t)(h << 7) * HWN;
        float r[8];
#pragma unroll
        for (int j = 0; j < 8; ++j) {
            float x = a[(size_t)j * HWN];
            r[j] = __fmul_rn(x, x);
        }
        for (int i = 8; i < 128; i += 8) {
#pragma unroll
            for (int j = 0; j < 8; ++j) {
                float x = a[(size_t)(i + j) * HWN];
                r[j] = __fadd_rn(r[j], __fmul_rn(x, x));
            }
        }
        half_[h] = __fadd_rn(__fadd_rn(__fadd_rn(r[0], r[1]), __fadd_rn(r[2], r[3])),
                             __fadd_rn(__fadd_rn(r[4], r[5]), __fadd_rn(r[6], r[7])));
    }
    z2[n] = __fadd_rn(half_[0], half_[1]);
}

// ------- prep: E -> Eh/El f16 of 1024*E (+ zero flag counter) -------
// scale 1024 keeps the residual el in f16-normal range; epilogue divides by 2^10.
__global__ __launch_bounds__(256) void k_prepE(const float* __restrict__ E,
                                               ushort* __restrict__ Eh,
                                               ushort* __restrict__ El,
                                               int* __restrict__ flagCount) {
    if (blockIdx.x == 0 && threadIdx.x == 0) *flagCount = 0;
    int i4 = (blockIdx.x << 8) + threadIdx.x;        // 0..65535 float4s
    float4 v = *reinterpret_cast<const float4*>(&E[(size_t)i4 << 2]);
    v.x *= 1024.f; v.y *= 1024.f; v.z *= 1024.f; v.w *= 1024.f;   // exact
    ushort4 h, l;
    h.x = f2h(v.x); l.x = f2h(v.x - h2f(h.x));
    h.y = f2h(v.y); l.y = f2h(v.y - h2f(h.y));
    h.z = f2h(v.z); l.z = f2h(v.z - h2f(h.z));
    h.w = f2h(v.w); l.w = f2h(v.w - h2f(h.w));
    *reinterpret_cast<ushort4*>(&Eh[(size_t)i4 << 2]) = h;
    *reinterpret_cast<ushort4*>(&El[(size_t)i4 << 2]) = l;
}

// --- MFMA distance pass: LDS-staged f16 2-term, XCD-aware block mapping ---
// acc = 1024 * (zh·eh + zh·el) ≈ 1024 * z·e ; dropped zl·e: sigma(2dot)~4e-6 << MARGIN
__global__ __launch_bounds__(256) void k_dist_mfma(const ushort* __restrict__ Zh,
                                                   const ushort* __restrict__ Eh,
                                                   const ushort* __restrict__ El,
                                                   const float* __restrict__ e2,
                                                   float* __restrict__ part) {
    __shared__ ushort zh[128][44], eh[128][44], el[128][44]; // 33792 B (pitch 88B: 2-way banks)
    __shared__ float red[128][2][3];                         //  3072 B

    const int B = blockIdx.x;          // 2048 blocks
    // XCD-aware: blocks round-robin XCDs; give each XCD a contiguous rb sweep
    // with the 8 cb-slices of one rb adjacent -> Zh L2-resident per XCD.
    const int xcd = B & 7;
    const int j = B >> 3;              // 0..255
    const int cb = j & 7;
    const int rb = (xcd << 5) + (j >> 3);
    const int n0 = rb << 7, c0 = cb << 7;
    const int th = threadIdx.x;
    const int wid = th >> 6, lane = th & 63;
    const int wr = wid >> 1, wc = wid & 1;
    const int fr = lane & 15, kg = (lane >> 4) << 3;

    f32x4 acc[4][4];
#pragma unroll
    for (int i = 0; i < 4; ++i)
#pragma unroll
        for (int jj = 0; jj < 4; ++jj) acc[i][jj] = (f32x4){0.f, 0.f, 0.f, 0.f};

    for (int kc = 0; kc < 8; ++kc) {
        __syncthreads();               // prev-iter frag reads done
#pragma unroll
        for (int s = th; s < 512; s += 256) {
            int row = s >> 2, c8 = (s & 3) << 3;
            size_t gz = (size_t)(n0 + row) * DD + (kc << 5) + c8;
            *reinterpret_cast<f16x8*>(&zh[row][c8]) = *reinterpret_cast<const f16x8*>(&Zh[gz]);
            size_t ge = (size_t)(c0 + row) * DD + (kc << 5) + c8;
            *reinterpret_cast<f16x8*>(&eh[row][c8]) = *reinterpret_cast<const f16x8*>(&Eh[ge]);
            *reinterpret_cast<f16x8*>(&el[row][c8]) = *reinterpret_cast<const f16x8*>(&El[ge]);
        }
        __syncthreads();

        f16x8 za[4], ea[4], eb[4];
#pragma unroll
        for (int mi = 0; mi < 4; ++mi) {
            int r = (wr << 6) + (mi << 4) + fr;
            za[mi] = *reinterpret_cast<f16x8*>(&zh[r][kg]);
        }
#pragma unroll
        for (int ni = 0; ni < 4; ++ni) {
            int c = (wc << 6) + (ni << 4) + fr;
            ea[ni] = *reinterpret_cast<f16x8*>(&eh[c][kg]);
            eb[ni] = *reinterpret_cast<f16x8*>(&el[c][kg]);
        }
#pragma unroll
        for (int mi = 0; mi < 4; ++mi)
#pragma unroll
            for (int ni = 0; ni < 4; ++ni) {
                acc[mi][ni] = __builtin_amdgcn_mfma_f32_16x16x32_f16(za[mi], ea[ni], acc[mi][ni], 0, 0, 0);
                acc[mi][ni] = __builtin_amdgcn_mfma_f32_16x16x32_f16(za[mi], eb[ni], acc[mi][ni], 0, 0, 0);
            }
    }

    float e2v[4];
#pragma unroll
    for (int ni = 0; ni < 4; ++ni) e2v[ni] = e2[c0 + (wc << 6) + (ni << 4) + fr];

    const int rg = lane >> 4;
#pragma unroll
    for (int mi = 0; mi < 4; ++mi) {
#pragma unroll
        for (int jj = 0; jj < 4; ++jj) {
            float m1 = __builtin_inff(), m2 = __builtin_inff(), bi = 3.4e38f;
#pragma unroll
            for (int ni = 0; ni < 4; ++ni) {
                float s = fmaf(-0x1p-9f, acc[mi][ni][jj], e2v[ni]);  // -2*dot, undo x1024
                float c = (float)(c0 + (wc << 6) + (ni << 4) + fr);
                if (s < m1)      { m2 = m1; m1 = s; bi = c; }
                else if (s < m2) { m2 = s; }
            }
#pragma unroll
            for (int m = 1; m <= 8; m <<= 1) {
                float om1 = __shfl_xor(m1, m);
                float om2 = __shfl_xor(m2, m);
                float obi = __shfl_xor(bi, m);
                if (om1 < m1)       { m2 = fminf(m1, om2); m1 = om1; bi = obi; }
                else if (om1 == m1) { bi = fminf(bi, obi); m2 = m1; }
                else                { m2 = fminf(m2, om1); }
            }
            if (fr == 0) {
                int row = (wr << 6) + (mi << 4) + (rg << 2) + jj;
                red[row][wc][0] = m1; red[row][wc][1] = m2; red[row][wc][2] = bi;
            }
        }
    }
    __syncthreads();
    if (th < 128) {
        float M1 = red[th][0][0], M2 = red[th][0][1], I = red[th][0][2];
        float v1 = red[th][1][0], v2 = red[th][1][1], vi = red[th][1][2];
        if (v1 < M1)       { M2 = fminf(M1, v2); M1 = v1; I = vi; }
        else if (v1 == M1) { I = fminf(I, vi); M2 = M1; }
        else               { M2 = fminf(M2, v1); }
        size_t p = ((size_t)(n0 + th) * 8 + cb) * 3;
        part[p] = M1; part[p + 1] = M2; part[p + 2] = I;
    }
}

// ------- combine 8 code-slices -> bestIdx + compacted near-tie list -------
__global__ __launch_bounds__(256) void k_combine(const float* __restrict__ part,
                                                 int* __restrict__ bestIdx,
                                                 int* __restrict__ flagList,
                                                 int* __restrict__ flagCount) {
    int n = (blockIdx.x << 8) + threadIdx.x;
    const float* p = part + (size_t)n * 24;
    float M1 = __builtin_inff(), M2 = __builtin_inff(), I = 3.4e38f;
    for (int c = 0; c < 8; ++c) {
        float v1 = p[c * 3], v2 = p[c * 3 + 1], vi = p[c * 3 + 2];
        if (v1 < M1)       { M2 = fminf(M1, v2); M1 = v1; I = vi; }
        else if (v1 == M1) { I = fminf(I, vi); M2 = M1; }
        else               { M2 = fminf(M2, v1); }
    }
    bestIdx[n] = (int)I;
    if (M2 - M1 < MARGIN) {
        int pos = atomicAdd(flagCount, 1);
        flagList[pos] = n;
    }
}

// ---- block-parallel np-f32-grid re-argmin: 4 rows x 16 codes x 4 d-slices ----
__global__ __launch_bounds__(256) void k_refine2(const float* __restrict__ Z,
                                                 const float* __restrict__ E,
                                                 const float* __restrict__ e2,
                                                 const float* __restrict__ z2,
                                                 int* __restrict__ bestIdx,
                                                 const int* __restrict__ flagList,
                                                 const int* __restrict__ flagCount) {
    __shared__ float ec[16][257];      // 16448 B: 16-code E chunk
    __shared__ float zr4[4][257];      //  4112 B: 4 z rows
    __shared__ double pd[16][4][4];    //  2048 B: partial dots (code, row, slice)
    __shared__ int rown[4];
    __shared__ float rz2[4];

    const int th = threadIdx.x;
    const int cl = th & 15;            // code-in-chunk
    const int rr = (th >> 4) & 3;      // row
    const int sl = th >> 6;            // d-slice (64 d each)
    const int cnt = *flagCount;

    for (int grp = blockIdx.x; grp * 4 < cnt; grp += (int)gridDim.x) {
        __syncthreads();               // protect rown/zr4/rz2 vs previous group
        if (th < 4) {
            int i = grp * 4 + th;
            if (i >= cnt) i = cnt - 1; // duplicate row: identical result, benign
            int n = flagList[i];
            rown[th] = n;
            rz2[th] = z2[n];
        }
        __syncthreads();
        for (int li = th; li < 1024; li += 256) {
            int r = li >> 8, d = li & 255;
            int n = rown[r];
            zr4[r][d] = Z[(size_t)(((n >> 10) << 8) + d) * HWN + (n & 1023)];
        }
        float gbest = __builtin_inff();
        int bi = 0;
        __syncthreads();

        for (int ch = 0; ch < 64; ++ch) {
            // stage 16 codes (coalesced float4); safe: prev compute done at barrier-2
#pragma unroll
            for (int j = 0; j < 4; ++j) {
                int li4 = (j << 8) + th;
                int c = li4 >> 6, d4 = (li4 & 63) << 2;
                *reinterpret_cast<float4*>(&ec[c][d4]) =
                    *reinterpret_cast<const float4*>(&E[(size_t)((ch << 4) + c) * DD + d4]);
            }
            // consume pd of chunk ch-1 (written before barrier-2 of prev iter)
            if (sl == 0 && ch > 0) {
                double dot = (pd[cl][rr][0] + pd[cl][rr][1]) + (pd[cl][rr][2] + pd[cl][rr][3]);
                int k = ((ch - 1) << 4) + cl;
                float c = (float)dot;
                float t2 = __fmul_rn(2.0f, c);
                float gg = __fsub_rn(__fadd_rn(rz2[rr], e2[k]), t2);
                if (gg < gbest) { gbest = gg; bi = k; }
            }
            __syncthreads();           // barrier-1: ec ready; pd(ch-1) consumed
            {
                const int db = sl << 6;
                double s0 = 0, s1 = 0, s2 = 0, s3 = 0;
#pragma unroll
                for (int d = 0; d < 64; d += 4) {
                    s0 += (double)ec[cl][db + d]     * zr4[rr][db + d];
                    s1 += (double)ec[cl][db + d + 1] * zr4[rr][db + d + 1];
                    s2 += (double)ec[cl][db + d + 2] * zr4[rr][db + d + 2];
                    s3 += (double)ec[cl][db + d + 3] * zr4[rr][db + d + 3];
                }
                pd[cl][rr][sl] = (s0 + s1) + (s2 + s3);
            }
            __syncthreads();           // barrier-2: pd ready; ec reads done
        }
        if (sl == 0) {
            {
                double dot = (pd[cl][rr][0] + pd[cl][rr][1]) + (pd[cl][rr][2] + pd[cl][rr][3]);
                int k = (63 << 4) + cl;
                float c = (float)dot;
                float t2 = __fmul_rn(2.0f, c);
                float gg = __fsub_rn(__fadd_rn(rz2[rr], e2[k]), t2);
                if (gg < gbest) { gbest = gg; bi = k; }
            }
#pragma unroll
            for (int m = 1; m <= 8; m <<= 1) {
                float og = __shfl_xor(gbest, m);
                int oi = __shfl_xor(bi, m);
                if (og < gbest || (og == gbest && oi < bi)) { gbest = og; bi = oi; }
            }
            if (cl == 0) bestIdx[rown[rr]] = bi;
        }
    }
}

// ======== fp32 fallback distance pass (used if ws too small) ========
#define UPD(m1, m2, i1, s, k)                            \
    do {                                                 \
        if ((s) < (m1)) { m2 = m1; m1 = (s); i1 = (k); } \
        else if ((s) < (m2)) { m2 = (s); }               \
    } while (0)

#define FMAJ(j, EV, C)                                   \
    acc[0][j] = fmaf(z4.x, EV.C, acc[0][j]);             \
    acc[1][j] = fmaf(z4.y, EV.C, acc[1][j]);             \
    acc[2][j] = fmaf(z4.z, EV.C, acc[2][j]);             \
    acc[3][j] = fmaf(z4.w, EV.C, acc[3][j]);

#define UROUND(u, C)                                                          \
    {                                                                         \
        float4 z4 = *reinterpret_cast<const float4*>(&zs[dq + u][ty4]);       \
        FMAJ(0, e0, C) FMAJ(1, e1, C) FMAJ(2, e2v, C) FMAJ(3, e3, C)          \
        FMAJ(4, e4, C) FMAJ(5, e5, C) FMAJ(6, e6, C) FMAJ(7, e7, C)           \
    }

__global__ __launch_bounds__(256, 3) void k_dist_f32(const float* __restrict__ Z,
                                                     const float* __restrict__ E,
                                                     const float* __restrict__ e2,
                                                     int* __restrict__ bestIdx) {
    __shared__ float zs[64][68];
    __shared__ float es[128][68];
    const int th = threadIdx.x;
    const int n0 = blockIdx.x << 6;
    const int b = n0 >> 10;
    const int hw0 = n0 & 1023;
    const int tx = th & 15;
    const int ty = th >> 4;
    const int ty4 = ty << 2;
    float m1[4], m2[4];
    int idx[4];
#pragma unroll
    for (int i = 0; i < 4; ++i) { m1[i] = __builtin_inff(); m2[i] = __builtin_inff(); idx[i] = 0; }
    for (int ct = 0; ct < 8; ++ct) {
        float acc[4][8];
#pragma unroll
        for (int i = 0; i < 4; ++i)
#pragma unroll
            for (int j = 0; j < 8; ++j) acc[i][j] = 0.f;
        for (int dc = 0; dc < 4; ++dc) {
            __syncthreads();
#pragma unroll
            for (int j = 0; j < 4; ++j) {
                int i4 = (j << 8) + th;
                int dd = i4 >> 4;
                int rr = (i4 & 15) << 2;
                *reinterpret_cast<float4*>(&zs[dd][rr]) =
                    *reinterpret_cast<const float4*>(
                        &Z[(size_t)((b << 8) + (dc << 6) + dd) * HWN + hw0 + rr]);
            }
#pragma unroll
            for (int j = 0; j < 8; ++j) {
                int i4 = (j << 8) + th;
                int c = i4 >> 4;
                int d4 = (i4 & 15) << 2;
                *reinterpret_cast<float4*>(&es[c][d4]) =
                    *reinterpret_cast<const float4*>(
                        &E[(size_t)((ct << 7) + c) * DD + (dc << 6) + d4]);
            }
            __syncthreads();
#pragma unroll
            for (int dq = 0; dq < 64; dq += 4) {
                float4 e0 = *reinterpret_cast<const float4*>(&es[tx][dq]);
                float4 e1 = *reinterpret_cast<const float4*>(&es[tx + 16][dq]);
                float4 e2v = *reinterpret_cast<const float4*>(&es[tx + 32][dq]);
                float4 e3 = *reinterpret_cast<const float4*>(&es[tx + 48][dq]);
                float4 e4 = *reinterpret_cast<const float4*>(&es[tx + 64][dq]);
                float4 e5 = *reinterpret_cast<const float4*>(&es[tx + 80][dq]);
                float4 e6 = *reinterpret_cast<const float4*>(&es[tx + 96][dq]);
                float4 e7 = *reinterpret_cast<const float4*>(&es[tx + 112][dq]);
                UROUND(0, x)
                UROUND(1, y)
                UROUND(2, z)
                UROUND(3, w)
            }
        }
#pragma unroll
        for (int j = 0; j < 8; ++j) {
            int c = (ct << 7) + tx + (j << 4);
            float en = e2[c];
#pragma unroll
            for (int i = 0; i < 4; ++i) {
                float s = fmaf(-2.f, acc[i][j], en);
                UPD(m1[i], m2[i], idx[i], s, c);
            }
        }
    }
    __syncthreads();
    float* red = &es[0][0];
#pragma unroll
    for (int i = 0; i < 4; ++i) {
        int r = ty4 + i;
        int base = ((r << 4) + tx) * 3;
        red[base] = m1[i]; red[base + 1] = m2[i]; red[base + 2] = (float)idx[i];
    }
    __syncthreads();
    if (th < 64) {
        float M1 = __builtin_inff(), M2 = __builtin_inff(), I = 3.4e38f;
        for (int t = 0; t < 16; ++t) {
            int base = ((th << 4) + t) * 3;
            float v1 = red[base], v2 = red[base + 1], vi = red[base + 2];
            if (v1 < M1)       { M2 = fminf(M1, v2); M1 = v1; I = vi; }
            else if (v1 == M1) { I = fminf(I, vi); M2 = fminf(M2, v1); M2 = fminf(M2, v2); }
            else               { M2 = fminf(M2, v1); }
        }
        int id = (int)I;
        bestIdx[n0 + th] = (M2 - M1 < MARGIN) ? (id | FLAGBIT) : id;
    }
}

// -------- fallback-path refine (FLAGBIT scan, unchanged semantics) --------
__global__ __launch_bounds__(64) void k_refine(const float* __restrict__ Z,
                                               const float* __restrict__ E,
                                               const float* __restrict__ e2,
                                               const float* __restrict__ z2,
                                               int* __restrict__ bestIdx) {
    __shared__ float zr[DD];
    const int l = threadIdx.x;
    for (int i = 0; i < 16; ++i) {
        int n = (blockIdx.x << 4) + i;
        if (!(bestIdx[n] & FLAGBIT)) continue;
        int b = n >> 10, hw = n & 1023;
        __syncthreads();
#pragma unroll
        for (int j = 0; j < 4; ++j)
            zr[(l << 2) + j] = Z[(size_t)((b << 8) + (l << 2) + j) * HWN + hw];
        __syncthreads();
        const float z2v = z2[n];
        float gbest = __builtin_inff();
        int bi = KK;
        for (int kk = 0; kk < 16; ++kk) {
            int k = (kk << 6) + l;
            double dot = 0.0;
            for (int d = 0; d < DD; d += 4) {
                float4 e4 = *reinterpret_cast<const float4*>(&E[(size_t)k * DD + d]);
                dot += (double)e4.x * zr[d]     + (double)e4.y * zr[d + 1]
                     + (double)e4.z * zr[d + 2] + (double)e4.w * zr[d + 3];
            }
            float c = (float)dot;
            float t = __fmul_rn(2.0f, c);
            float gg = __fsub_rn(__fadd_rn(z2v, e2[k]), t);
            if (gg < gbest) { gbest = gg; bi = k; }
        }
#pragma unroll
        for (int off = 32; off > 0; off >>= 1) {
            float og = __shfl_down(gbest, off);
            int oi = __shfl_down(bi, off);
            if (og < gbest || (og == gbest && oi < bi)) { gbest = og; bi = oi; }
        }
        if (l == 0) bestIdx[n] = bi;
    }
}

// -------- outputs: idx, loss (NHWC), z_q (NCHW) --------
__global__ __launch_bounds__(256) void k_out(const float* __restrict__ Z,
                                             const float* __restrict__ E,
                                             const int* __restrict__ bestIdx,
                                             float* __restrict__ out) {
    __shared__ float zc[64][68];
    __shared__ int idxs[64];
    const int th = threadIdx.x;
    const int n0 = blockIdx.x << 6;
    const int b = n0 >> 10;
    const int hw0 = n0 & 1023;

    if (th < 64) {
        int id = bestIdx[n0 + th] & 1023;
        idxs[th] = id;
        out[IDX_OFF + n0 + th] = (float)id;
    }
    __syncthreads();

    for (int dc = 0; dc < 4; ++dc) {
        __syncthreads();
#pragma unroll
        for (int j = 0; j < 16; ++j) {
            int li = (j << 8) + th;
            int dd = li >> 6;
            int r = li & 63;
            zc[r][dd] = Z[(size_t)((b << 8) + (dc << 6) + dd) * HWN + hw0 + r];
        }
        __syncthreads();
#pragma unroll
        for (int j = 0; j < 4; ++j) {
            int i4 = (j << 8) + th;
            int r = i4 >> 4;
            int f = (i4 & 15) << 2;
            float4 e4 = *reinterpret_cast<const float4*>(
                &E[(size_t)idxs[r] * DD + (dc << 6) + f]);
            float4 z4 = *reinterpret_cast<const float4*>(&zc[r][f]);
            float4 o;
            o.x = (e4.x - z4.x) * (e4.x - z4.x);
            o.y = (e4.y - z4.y) * (e4.y - z4.y);
            o.z = (e4.z - z4.z) * (e4.z - z4.z);
            o.w = (e4.w - z4.w) * (e4.w - z4.w);
            *reinterpret_cast<float4*>(
                &out[LOSS_OFF + (size_t)(n0 + r) * DD + (dc << 6) + f]) = o;
        }
#pragma unroll
        for (int j = 0; j < 16; ++j) {
            int li = (j << 8) + th;
            int dd = li >> 6;
            int r = li & 63;
            out[ZQ_OFF + (size_t)((b << 8) + (dc << 6) + dd) * HWN + hw0 + r] =
                E[(size_t)idxs[r] * DD + (dc << 6) + dd];
        }
    }
}

extern "C" void kernel_launch(void* const* d_in, const int* in_sizes, int n_in,
                              void* d_out, int out_size, void* d_ws, size_t ws_size,
                              hipStream_t stream) {
    const float* Z = (const float*)d_in[0];           // [32,256,32,32] f32
    const float* E = (const float*)d_in[1];           // [1024,256] f32
    float* out = (float*)d_out;
    char* ws = (char*)d_ws;
    float* e2 = (float*)ws;
    float* z2 = (float*)(ws + 4096);
    int* bestIdx = (int*)(ws + 135168);

    k_e2<<<KK / 64, 64, 0, stream>>>(E, e2);

    if (ws_size >= WS_NEED) {
        float* part = (float*)(ws + 266240);
        ushort* Eh = (ushort*)(ws + 3411968);
        ushort* El = (ushort*)(ws + 3936256);
        ushort* Zh = (ushort*)(ws + 4460544);
        int* flagCount = (int*)(ws + 38014976);
        int* flagList = (int*)(ws + 38015040);
        k_prepE<<<256, 256, 0, stream>>>(E, Eh, El, flagCount);
        k_prepZ2<<<2048, 256, 0, stream>>>(Z, Zh, z2);
        k_dist_mfma<<<2048, 256, 0, stream>>>(Zh, Eh, El, e2, part);
        k_combine<<<NN / 256, 256, 0, stream>>>(part, bestIdx, flagList, flagCount);
        k_refine2<<<512, 256, 0, stream>>>(Z, E, e2, z2, bestIdx, flagList, flagCount);
    } else {
        k_z2<<<NN / 256, 256, 0, stream>>>(Z, z2);
        k_dist_f32<<<NN / 64, 256, 0, stream>>>(Z, E, e2, bestIdx);
        k_refine<<<NN / 16, 64, 0, stream>>>(Z, E, e2, z2, bestIdx);
    }

    k_out<<<NN / 64, 256, 0, stream>>>(Z, E, bestIdx, out);
}

// Round 13
// 209.234 us; speedup vs baseline: 1.5707x; 1.2212x over previous
//
#include <hip/hip_runtime.h>

#define DD 256
#define HWN 1024
#define NN 32768
#define KK 1024
#define MARGIN 1e-4f
#define FLAGBIT (1 << 30)

// f32-element offsets into d_out (out_size = 16809984 floats):
#define ZQ_OFF   0          // z_q   [32,256,32,32]
#define IDX_OFF  8388608    // idx   [32768]
#define LOSS_OFF 8421376    // loss  [32,32,32,256] (NHWC)

// ws layout (MFMA path needs WS_NEED bytes; else fp32 fallback):
// [0, 4096)            float e2[1024]
// [4096, 135168)       float z2[32768]
// [135168, 266240)     int   bestIdx[32768]
// [266240, 3411968)    float part[32768][8][3]
// [3411968, 3936256)   ushort Eh[1024][256]   (f16 of 1024*E)
// [3936256, 4460544)   ushort El[1024][256]   (f16 residual of 1024*E)
// [4460544, 21237760)  ushort Zh[32768][256]  (f16 of Z, [n][d])
// [21237760, 38014976) (unused)
// [38014976, 38015040) int flagCount
// [38015040, 38146112) int flagList[32768]
#define WS_NEED 38146112

typedef __attribute__((ext_vector_type(8))) _Float16 f16x8;
typedef __attribute__((ext_vector_type(4))) float f32x4;

__device__ __forceinline__ ushort f2h(float x) {
    _Float16 h = (_Float16)x;                  // RNE
    return *reinterpret_cast<ushort*>(&h);
}
__device__ __forceinline__ float h2f(ushort u) {
    _Float16 h = *reinterpret_cast<_Float16*>(&u);
    return (float)h;
}

// ---------------- e2[k]: numpy-exact f32 codebook norms ----------------
__global__ __launch_bounds__(64) void k_e2(const float* __restrict__ E,
                                           float* __restrict__ e2) {
    int k = (blockIdx.x << 6) + threadIdx.x;
    const float* row = E + (size_t)k * DD;
    float half_[2];
#pragma unroll
    for (int h = 0; h < 2; ++h) {
        const float* a = row + (h << 7);
        float r[8];
#pragma unroll
        for (int j = 0; j < 8; ++j) r[j] = __fmul_rn(a[j], a[j]);
        for (int i = 8; i < 128; i += 8) {
#pragma unroll
            for (int j = 0; j < 8; ++j) {
                float x = a[i + j];
                r[j] = __fadd_rn(r[j], __fmul_rn(x, x));
            }
        }
        half_[h] = __fadd_rn(__fadd_rn(__fadd_rn(r[0], r[1]), __fadd_rn(r[2], r[3])),
                             __fadd_rn(__fadd_rn(r[4], r[5]), __fadd_rn(r[6], r[7])));
    }
    e2[k] = __fadd_rn(half_[0], half_[1]);
}

// -- fused: Z transpose tile -> Zh f16 [n][d] + numpy-exact z2 --
__global__ __launch_bounds__(256) void k_prepZ2(const float* __restrict__ Z,
                                                ushort* __restrict__ Zh,
                                                float* __restrict__ z2) {
    __shared__ float zc[16][257];      // 16448 B
    const int g = blockIdx.x;          // 2048 blocks: 16 rows each
    const int b = g >> 6;
    const int hw0 = (g & 63) << 4;
    const int th = threadIdx.x;
    const int n0 = (b << 10) + hw0;

#pragma unroll
    for (int j = 0; j < 16; ++j) {
        int li = (j << 8) + th;        // 0..4095
        int d = li >> 4;
        int hl = li & 15;
        zc[hl][d] = Z[(size_t)((b << 8) + d) * HWN + hw0 + hl];
    }
    __syncthreads();

    // f16 (RNE), [n][d] layout, 32B/thread contiguous
    {
        int r = th >> 4, c = th & 15;
        ushort hs[16];
#pragma unroll
        for (int i = 0; i < 16; ++i) hs[i] = f2h(zc[r][(c << 4) + i]);
        size_t addr = (size_t)(n0 + r) * DD + (c << 4);
        *reinterpret_cast<f16x8*>(&Zh[addr]) = *reinterpret_cast<f16x8*>(&hs[0]);
        *reinterpret_cast<f16x8*>(&Zh[addr + 8]) = *reinterpret_cast<f16x8*>(&hs[8]);
    }

    // z2: numpy pairwise (identical op order to the validated k_z2)
    if (th < 16) {
        const float* rowp = &zc[th][0];
        float half_[2];
#pragma unroll
        for (int h = 0; h < 2; ++h) {
            const float* a = rowp + (h << 7);
            float r[8];
#pragma unroll
            for (int j = 0; j < 8; ++j) r[j] = __fmul_rn(a[j], a[j]);
            for (int i = 8; i < 128; i += 8) {
#pragma unroll
                for (int j = 0; j < 8; ++j) {
                    float x = a[i + j];
                    r[j] = __fadd_rn(r[j], __fmul_rn(x, x));
                }
            }
            half_[h] = __fadd_rn(__fadd_rn(__fadd_rn(r[0], r[1]), __fadd_rn(r[2], r[3])),
                                 __fadd_rn(__fadd_rn(r[4], r[5]), __fadd_rn(r[6], r[7])));
        }
        z2[n0 + th] = __fadd_rn(half_[0], half_[1]);
    }
}

// ---------------- z2 standalone (fallback path only) ----------------
__global__ __launch_bounds__(256) void k_z2(const float* __restrict__ Z,
                                            float* __restrict__ z2) {
    int n = (blockIdx.x << 8) + threadIdx.x;
    int b = n >> 10, hw = n & 1023;
    const float* base = Z + (size_t)(b << 8) * HWN + hw;
    float half_[2];
#pragma unroll
    for (int h = 0; h < 2; ++h) {
        const float* a = base + (size_t)(h << 7) * HWN;
        float r[8];
#pragma unroll
        for (int j = 0; j < 8; ++j) {
            float x = a[(size_t)j * HWN];
            r[j] = __fmul_rn(x, x);
        }
        for (int i = 8; i < 128; i += 8) {
#pragma unroll
            for (int j = 0; j < 8; ++j) {
                float x = a[(size_t)(i + j) * HWN];
                r[j] = __fadd_rn(r[j], __fmul_rn(x, x));
            }
        }
        half_[h] = __fadd_rn(__fadd_rn(__fadd_rn(r[0], r[1]), __fadd_rn(r[2], r[3])),
                             __fadd_rn(__fadd_rn(r[4], r[5]), __fadd_rn(r[6], r[7])));
    }
    z2[n] = __fadd_rn(half_[0], half_[1]);
}

// ------- prep: E -> Eh/El f16 of 1024*E (+ zero flag counter) -------
__global__ __launch_bounds__(256) void k_prepE(const float* __restrict__ E,
                                               ushort* __restrict__ Eh,
                                               ushort* __restrict__ El,
                                               int* __restrict__ flagCount) {
    if (blockIdx.x == 0 && threadIdx.x == 0) *flagCount = 0;
    int i4 = (blockIdx.x << 8) + threadIdx.x;        // 0..65535 float4s
    float4 v = *reinterpret_cast<const float4*>(&E[(size_t)i4 << 2]);
    v.x *= 1024.f; v.y *= 1024.f; v.z *= 1024.f; v.w *= 1024.f;   // exact
    ushort4 h, l;
    h.x = f2h(v.x); l.x = f2h(v.x - h2f(h.x));
    h.y = f2h(v.y); l.y = f2h(v.y - h2f(h.y));
    h.z = f2h(v.z); l.z = f2h(v.z - h2f(h.z));
    h.w = f2h(v.w); l.w = f2h(v.w - h2f(h.w));
    *reinterpret_cast<ushort4*>(&Eh[(size_t)i4 << 2]) = h;
    *reinterpret_cast<ushort4*>(&El[(size_t)i4 << 2]) = l;
}

// --- MFMA distance pass: LDS-staged f16 2-term, XCD-aware block mapping ---
__global__ __launch_bounds__(256) void k_dist_mfma(const ushort* __restrict__ Zh,
                                                   const ushort* __restrict__ Eh,
                                                   const ushort* __restrict__ El,
                                                   const float* __restrict__ e2,
                                                   float* __restrict__ part) {
    __shared__ ushort zh[128][44], eh[128][44], el[128][44]; // 33792 B
    __shared__ float red[128][2][3];                         //  3072 B

    const int B = blockIdx.x;          // 2048 blocks
    const int xcd = B & 7;
    const int j = B >> 3;              // 0..255
    const int cb = j & 7;
    const int rb = (xcd << 5) + (j >> 3);
    const int n0 = rb << 7, c0 = cb << 7;
    const int th = threadIdx.x;
    const int wid = th >> 6, lane = th & 63;
    const int wr = wid >> 1, wc = wid & 1;
    const int fr = lane & 15, kg = (lane >> 4) << 3;

    f32x4 acc[4][4];
#pragma unroll
    for (int i = 0; i < 4; ++i)
#pragma unroll
        for (int jj = 0; jj < 4; ++jj) acc[i][jj] = (f32x4){0.f, 0.f, 0.f, 0.f};

    for (int kc = 0; kc < 8; ++kc) {
        __syncthreads();               // prev-iter frag reads done
#pragma unroll
        for (int s = th; s < 512; s += 256) {
            int row = s >> 2, c8 = (s & 3) << 3;
            size_t gz = (size_t)(n0 + row) * DD + (kc << 5) + c8;
            *reinterpret_cast<f16x8*>(&zh[row][c8]) = *reinterpret_cast<const f16x8*>(&Zh[gz]);
            size_t ge = (size_t)(c0 + row) * DD + (kc << 5) + c8;
            *reinterpret_cast<f16x8*>(&eh[row][c8]) = *reinterpret_cast<const f16x8*>(&Eh[ge]);
            *reinterpret_cast<f16x8*>(&el[row][c8]) = *reinterpret_cast<const f16x8*>(&El[ge]);
        }
        __syncthreads();

        f16x8 za[4], ea[4], eb[4];
#pragma unroll
        for (int mi = 0; mi < 4; ++mi) {
            int r = (wr << 6) + (mi << 4) + fr;
            za[mi] = *reinterpret_cast<f16x8*>(&zh[r][kg]);
        }
#pragma unroll
        for (int ni = 0; ni < 4; ++ni) {
            int c = (wc << 6) + (ni << 4) + fr;
            ea[ni] = *reinterpret_cast<f16x8*>(&eh[c][kg]);
            eb[ni] = *reinterpret_cast<f16x8*>(&el[c][kg]);
        }
#pragma unroll
        for (int mi = 0; mi < 4; ++mi)
#pragma unroll
            for (int ni = 0; ni < 4; ++ni) {
                acc[mi][ni] = __builtin_amdgcn_mfma_f32_16x16x32_f16(za[mi], ea[ni], acc[mi][ni], 0, 0, 0);
                acc[mi][ni] = __builtin_amdgcn_mfma_f32_16x16x32_f16(za[mi], eb[ni], acc[mi][ni], 0, 0, 0);
            }
    }

    float e2v[4];
#pragma unroll
    for (int ni = 0; ni < 4; ++ni) e2v[ni] = e2[c0 + (wc << 6) + (ni << 4) + fr];

    const int rg = lane >> 4;
#pragma unroll
    for (int mi = 0; mi < 4; ++mi) {
#pragma unroll
        for (int jj = 0; jj < 4; ++jj) {
            float m1 = __builtin_inff(), m2 = __builtin_inff(), bi = 3.4e38f;
#pragma unroll
            for (int ni = 0; ni < 4; ++ni) {
                float s = fmaf(-0x1p-9f, acc[mi][ni][jj], e2v[ni]);  // -2*dot, undo x1024
                float c = (float)(c0 + (wc << 6) + (ni << 4) + fr);
                if (s < m1)      { m2 = m1; m1 = s; bi = c; }
                else if (s < m2) { m2 = s; }
            }
#pragma unroll
            for (int m = 1; m <= 8; m <<= 1) {
                float om1 = __shfl_xor(m1, m);
                float om2 = __shfl_xor(m2, m);
                float obi = __shfl_xor(bi, m);
                if (om1 < m1)       { m2 = fminf(m1, om2); m1 = om1; bi = obi; }
                else if (om1 == m1) { bi = fminf(bi, obi); m2 = m1; }
                else                { m2 = fminf(m2, om1); }
            }
            if (fr == 0) {
                int row = (wr << 6) + (mi << 4) + (rg << 2) + jj;
                red[row][wc][0] = m1; red[row][wc][1] = m2; red[row][wc][2] = bi;
            }
        }
    }
    __syncthreads();
    if (th < 128) {
        float M1 = red[th][0][0], M2 = red[th][0][1], I = red[th][0][2];
        float v1 = red[th][1][0], v2 = red[th][1][1], vi = red[th][1][2];
        if (v1 < M1)       { M2 = fminf(M1, v2); M1 = v1; I = vi; }
        else if (v1 == M1) { I = fminf(I, vi); M2 = M1; }
        else               { M2 = fminf(M2, v1); }
        size_t p = ((size_t)(n0 + th) * 8 + cb) * 3;
        part[p] = M1; part[p + 1] = M2; part[p + 2] = I;
    }
}

// ------- combine 8 code-slices -> bestIdx + compacted near-tie list -------
__global__ __launch_bounds__(256) void k_combine(const float* __restrict__ part,
                                                 int* __restrict__ bestIdx,
                                                 int* __restrict__ flagList,
                                                 int* __restrict__ flagCount) {
    int n = (blockIdx.x << 8) + threadIdx.x;
    const float* p = part + (size_t)n * 24;
    float M1 = __builtin_inff(), M2 = __builtin_inff(), I = 3.4e38f;
    for (int c = 0; c < 8; ++c) {
        float v1 = p[c * 3], v2 = p[c * 3 + 1], vi = p[c * 3 + 2];
        if (v1 < M1)       { M2 = fminf(M1, v2); M1 = v1; I = vi; }
        else if (v1 == M1) { I = fminf(I, vi); M2 = M1; }
        else               { M2 = fminf(M2, v1); }
    }
    bestIdx[n] = (int)I;
    if (M2 - M1 < MARGIN) {
        int pos = atomicAdd(flagCount, 1);
        flagList[pos] = n;
    }
}

// ---- np-f32-grid re-argmin: 1 row/block, 16 code-groups x 16 lanes, no E staging ----
__global__ __launch_bounds__(256) void k_refine3(const float* __restrict__ Z,
                                                 const float* __restrict__ E,
                                                 const float* __restrict__ e2,
                                                 const float* __restrict__ z2,
                                                 int* __restrict__ bestIdx,
                                                 const int* __restrict__ flagList,
                                                 const int* __restrict__ flagCount) {
    __shared__ float zsh[DD];
    __shared__ float gbv[16];
    __shared__ int gbi[16];
    const int th = threadIdx.x;
    const int g = th >> 4;             // code group 0..15
    const int l = th & 15;             // lane in group
    const int cnt = *flagCount;

    for (int i = blockIdx.x; i < cnt; i += (int)gridDim.x) {
        const int n = flagList[i];
        const int b = n >> 10, hw = n & 1023;
        __syncthreads();               // protect zsh/gbv/gbi from previous row
        if (th < DD) zsh[th] = Z[(size_t)((b << 8) + th) * HWN + hw];
        __syncthreads();
        float zr[16];
#pragma unroll
        for (int jq = 0; jq < 16; ++jq) zr[jq] = zsh[(l << 4) + jq];
        const float z2v = z2[n];
        float gbest = __builtin_inff();
        int bi = 0;

        for (int it = 0; it < 64; ++it) {
            const int c = (it << 4) + g;              // ascending per group
            const float* er = &E[(size_t)c * DD + (l << 4)];
            float4 a0 = *reinterpret_cast<const float4*>(er);
            float4 a1 = *reinterpret_cast<const float4*>(er + 4);
            float4 a2 = *reinterpret_cast<const float4*>(er + 8);
            float4 a3 = *reinterpret_cast<const float4*>(er + 12);
            double s0 = (double)a0.x * zr[0]  + (double)a0.y * zr[1]
                      + (double)a0.z * zr[2]  + (double)a0.w * zr[3];
            double s1 = (double)a1.x * zr[4]  + (double)a1.y * zr[5]
                      + (double)a1.z * zr[6]  + (double)a1.w * zr[7];
            double s2 = (double)a2.x * zr[8]  + (double)a2.y * zr[9]
                      + (double)a2.z * zr[10] + (double)a2.w * zr[11];
            double s3 = (double)a3.x * zr[12] + (double)a3.y * zr[13]
                      + (double)a3.z * zr[14] + (double)a3.w * zr[15];
            double dot = (s0 + s1) + (s2 + s3);
#pragma unroll
            for (int m = 1; m <= 8; m <<= 1) dot += __shfl_xor(dot, m);  // 16-lane sum
            if (l == 0) {
                float cc = (float)dot;
                float t2 = __fmul_rn(2.0f, cc);
                float gg = __fsub_rn(__fadd_rn(z2v, e2[c]), t2);
                if (gg < gbest) { gbest = gg; bi = c; }   // lowest c wins ties
            }
        }
        if (l == 0) { gbv[g] = gbest; gbi[g] = bi; }
        __syncthreads();
        if (th == 0) {
            float best = gbv[0]; int bbi = gbi[0];
            for (int q = 1; q < 16; ++q) {
                float v = gbv[q]; int vi = gbi[q];
                if (v < best || (v == best && vi < bbi)) { best = v; bbi = vi; }
            }
            bestIdx[n] = bbi;
        }
    }
}

// ======== fp32 fallback distance pass (used if ws too small) ========
#define UPD(m1, m2, i1, s, k)                            \
    do {                                                 \
        if ((s) < (m1)) { m2 = m1; m1 = (s); i1 = (k); } \
        else if ((s) < (m2)) { m2 = (s); }               \
    } while (0)

#define FMAJ(j, EV, C)                                   \
    acc[0][j] = fmaf(z4.x, EV.C, acc[0][j]);             \
    acc[1][j] = fmaf(z4.y, EV.C, acc[1][j]);             \
    acc[2][j] = fmaf(z4.z, EV.C, acc[2][j]);             \
    acc[3][j] = fmaf(z4.w, EV.C, acc[3][j]);

#define UROUND(u, C)                                                          \
    {                                                                         \
        float4 z4 = *reinterpret_cast<const float4*>(&zs[dq + u][ty4]);       \
        FMAJ(0, e0, C) FMAJ(1, e1, C) FMAJ(2, e2v, C) FMAJ(3, e3, C)          \
        FMAJ(4, e4, C) FMAJ(5, e5, C) FMAJ(6, e6, C) FMAJ(7, e7, C)           \
    }

__global__ __launch_bounds__(256, 3) void k_dist_f32(const float* __restrict__ Z,
                                                     const float* __restrict__ E,
                                                     const float* __restrict__ e2,
                                                     int* __restrict__ bestIdx) {
    __shared__ float zs[64][68];
    __shared__ float es[128][68];
    const int th = threadIdx.x;
    const int n0 = blockIdx.x << 6;
    const int b = n0 >> 10;
    const int hw0 = n0 & 1023;
    const int tx = th & 15;
    const int ty = th >> 4;
    const int ty4 = ty << 2;
    float m1[4], m2[4];
    int idx[4];
#pragma unroll
    for (int i = 0; i < 4; ++i) { m1[i] = __builtin_inff(); m2[i] = __builtin_inff(); idx[i] = 0; }
    for (int ct = 0; ct < 8; ++ct) {
        float acc[4][8];
#pragma unroll
        for (int i = 0; i < 4; ++i)
#pragma unroll
            for (int j = 0; j < 8; ++j) acc[i][j] = 0.f;
        for (int dc = 0; dc < 4; ++dc) {
            __syncthreads();
#pragma unroll
            for (int j = 0; j < 4; ++j) {
                int i4 = (j << 8) + th;
                int dd = i4 >> 4;
                int rr = (i4 & 15) << 2;
                *reinterpret_cast<float4*>(&zs[dd][rr]) =
                    *reinterpret_cast<const float4*>(
                        &Z[(size_t)((b << 8) + (dc << 6) + dd) * HWN + hw0 + rr]);
            }
#pragma unroll
            for (int j = 0; j < 8; ++j) {
                int i4 = (j << 8) + th;
                int c = i4 >> 4;
                int d4 = (i4 & 15) << 2;
                *reinterpret_cast<float4*>(&es[c][d4]) =
                    *reinterpret_cast<const float4*>(
                        &E[(size_t)((ct << 7) + c) * DD + (dc << 6) + d4]);
            }
            __syncthreads();
#pragma unroll
            for (int dq = 0; dq < 64; dq += 4) {
                float4 e0 = *reinterpret_cast<const float4*>(&es[tx][dq]);
                float4 e1 = *reinterpret_cast<const float4*>(&es[tx + 16][dq]);
                float4 e2v = *reinterpret_cast<const float4*>(&es[tx + 32][dq]);
                float4 e3 = *reinterpret_cast<const float4*>(&es[tx + 48][dq]);
                float4 e4 = *reinterpret_cast<const float4*>(&es[tx + 64][dq]);
                float4 e5 = *reinterpret_cast<const float4*>(&es[tx + 80][dq]);
                float4 e6 = *reinterpret_cast<const float4*>(&es[tx + 96][dq]);
                float4 e7 = *reinterpret_cast<const float4*>(&es[tx + 112][dq]);
                UROUND(0, x)
                UROUND(1, y)
                UROUND(2, z)
                UROUND(3, w)
            }
        }
#pragma unroll
        for (int j = 0; j < 8; ++j) {
            int c = (ct << 7) + tx + (j << 4);
            float en = e2[c];
#pragma unroll
            for (int i = 0; i < 4; ++i) {
                float s = fmaf(-2.f, acc[i][j], en);
                UPD(m1[i], m2[i], idx[i], s, c);
            }
        }
    }
    __syncthreads();
    float* red = &es[0][0];
#pragma unroll
    for (int i = 0; i < 4; ++i) {
        int r = ty4 + i;
        int base = ((r << 4) + tx) * 3;
        red[base] = m1[i]; red[base + 1] = m2[i]; red[base + 2] = (float)idx[i];
    }
    __syncthreads();
    if (th < 64) {
        float M1 = __builtin_inff(), M2 = __builtin_inff(), I = 3.4e38f;
        for (int t = 0; t < 16; ++t) {
            int base = ((th << 4) + t) * 3;
            float v1 = red[base], v2 = red[base + 1], vi = red[base + 2];
            if (v1 < M1)       { M2 = fminf(M1, v2); M1 = v1; I = vi; }
            else if (v1 == M1) { I = fminf(I, vi); M2 = fminf(M2, v1); M2 = fminf(M2, v2); }
            else               { M2 = fminf(M2, v1); }
        }
        int id = (int)I;
        bestIdx[n0 + th] = (M2 - M1 < MARGIN) ? (id | FLAGBIT) : id;
    }
}

// -------- fallback-path refine (FLAGBIT scan, unchanged semantics) --------
__global__ __launch_bounds__(64) void k_refine(const float* __restrict__ Z,
                                               const float* __restrict__ E,
                                               const float* __restrict__ e2,
                                               const float* __restrict__ z2,
                                               int* __restrict__ bestIdx) {
    __shared__ float zr[DD];
    const int l = threadIdx.x;
    for (int i = 0; i < 16; ++i) {
        int n = (blockIdx.x << 4) + i;
        if (!(bestIdx[n] & FLAGBIT)) continue;
        int b = n >> 10, hw = n & 1023;
        __syncthreads();
#pragma unroll
        for (int j = 0; j < 4; ++j)
            zr[(l << 2) + j] = Z[(size_t)((b << 8) + (l << 2) + j) * HWN + hw];
        __syncthreads();
        const float z2v = z2[n];
        float gbest = __builtin_inff();
        int bi = KK;
        for (int kk = 0; kk < 16; ++kk) {
            int k = (kk << 6) + l;
            double dot = 0.0;
            for (int d = 0; d < DD; d += 4) {
                float4 e4 = *reinterpret_cast<const float4*>(&E[(size_t)k * DD + d]);
                dot += (double)e4.x * zr[d]     + (double)e4.y * zr[d + 1]
                     + (double)e4.z * zr[d + 2] + (double)e4.w * zr[d + 3];
            }
            float c = (float)dot;
            float t = __fmul_rn(2.0f, c);
            float gg = __fsub_rn(__fadd_rn(z2v, e2[k]), t);
            if (gg < gbest) { gbest = gg; bi = k; }
        }
#pragma unroll
        for (int off = 32; off > 0; off >>= 1) {
            float og = __shfl_down(gbest, off);
            int oi = __shfl_down(bi, off);
            if (og < gbest || (og == gbest && oi < bi)) { gbest = og; bi = oi; }
        }
        if (l == 0) bestIdx[n] = bi;
    }
}

// -------- outputs: idx, loss (NHWC), z_q (NCHW) --------
__global__ __launch_bounds__(256) void k_out(const float* __restrict__ Z,
                                             const float* __restrict__ E,
                                             const int* __restrict__ bestIdx,
                                             float* __restrict__ out) {
    __shared__ float zc[64][68];
    __shared__ int idxs[64];
    const int th = threadIdx.x;
    const int n0 = blockIdx.x << 6;
    const int b = n0 >> 10;
    const int hw0 = n0 & 1023;

    if (th < 64) {
        int id = bestIdx[n0 + th] & 1023;
        idxs[th] = id;
        out[IDX_OFF + n0 + th] = (float)id;
    }
    __syncthreads();

    for (int dc = 0; dc < 4; ++dc) {
        __syncthreads();
#pragma unroll
        for (int j = 0; j < 16; ++j) {
            int li = (j << 8) + th;
            int dd = li >> 6;
            int r = li & 63;
            zc[r][dd] = Z[(size_t)((b << 8) + (dc << 6) + dd) * HWN + hw0 + r];
        }
        __syncthreads();
#pragma unroll
        for (int j = 0; j < 4; ++j) {
            int i4 = (j << 8) + th;
            int r = i4 >> 4;
            int f = (i4 & 15) << 2;
            float4 e4 = *reinterpret_cast<const float4*>(
                &E[(size_t)idxs[r] * DD + (dc << 6) + f]);
            float4 z4 = *reinterpret_cast<const float4*>(&zc[r][f]);
            float4 o;
            o.x = (e4.x - z4.x) * (e4.x - z4.x);
            o.y = (e4.y - z4.y) * (e4.y - z4.y);
            o.z = (e4.z - z4.z) * (e4.z - z4.z);
            o.w = (e4.w - z4.w) * (e4.w - z4.w);
            *reinterpret_cast<float4*>(
                &out[LOSS_OFF + (size_t)(n0 + r) * DD + (dc << 6) + f]) = o;
        }
#pragma unroll
        for (int j = 0; j < 16; ++j) {
            int li = (j << 8) + th;
            int dd = li >> 6;
            int r = li & 63;
            out[ZQ_OFF + (size_t)((b << 8) + (dc << 6) + dd) * HWN + hw0 + r] =
                E[(size_t)idxs[r] * DD + (dc << 6) + dd];
        }
    }
}

extern "C" void kernel_launch(void* const* d_in, const int* in_sizes, int n_in,
                              void* d_out, int out_size, void* d_ws, size_t ws_size,
                              hipStream_t stream) {
    const float* Z = (const float*)d_in[0];           // [32,256,32,32] f32
    const float* E = (const float*)d_in[1];           // [1024,256] f32
    float* out = (float*)d_out;
    char* ws = (char*)d_ws;
    float* e2 = (float*)ws;
    float* z2 = (float*)(ws + 4096);
    int* bestIdx = (int*)(ws + 135168);

    k_e2<<<KK / 64, 64, 0, stream>>>(E, e2);

    if (ws_size >= WS_NEED) {
        float* part = (float*)(ws + 266240);
        ushort* Eh = (ushort*)(ws + 3411968);
        ushort* El = (ushort*)(ws + 3936256);
        ushort* Zh = (ushort*)(ws + 4460544);
        int* flagCount = (int*)(ws + 38014976);
        int* flagList = (int*)(ws + 38015040);
        k_prepE<<<256, 256, 0, stream>>>(E, Eh, El, flagCount);
        k_prepZ2<<<2048, 256, 0, stream>>>(Z, Zh, z2);
        k_dist_mfma<<<2048, 256, 0, stream>>>(Zh, Eh, El, e2, part);
        k_combine<<<NN / 256, 256, 0, stream>>>(part, bestIdx, flagList, flagCount);
        k_refine3<<<2048, 256, 0, stream>>>(Z, E, e2, z2, bestIdx, flagList, flagCount);
    } else {
        k_z2<<<NN / 256, 256, 0, stream>>>(Z, z2);
        k_dist_f32<<<NN / 64, 256, 0, stream>>>(Z, E, e2, bestIdx);
        k_refine<<<NN / 16, 64, 0, stream>>>(Z, E, e2, z2, bestIdx);
    }

    k_out<<<NN / 64, 256, 0, stream>>>(Z, E, bestIdx, out);
}

// Round 14
// 202.369 us; speedup vs baseline: 1.6240x; 1.0339x over previous
//
#include <hip/hip_runtime.h>

#define DD 256
#define HWN 1024
#define NN 32768
#define KK 1024
#define MARGIN 1e-4f
#define FLAGBIT (1 << 30)

// f32-element offsets into d_out (out_size = 16809984 floats):
#define ZQ_OFF   0          // z_q   [32,256,32,32]
#define IDX_OFF  8388608    // idx   [32768]
#define LOSS_OFF 8421376    // loss  [32,32,32,256] (NHWC)

// ws layout (MFMA path needs WS_NEED bytes; else fp32 fallback):
// [0, 4096)            float e2[1024]
// [4096, 135168)       float z2[32768]
// [135168, 266240)     int   bestIdx[32768]
// [266240, 3411968)    float part[32768][8][3]
// [3411968, 3936256)   ushort Eh[1024][256]   (f16 of 1024*E)
// [3936256, 4460544)   ushort El[1024][256]   (f16 residual of 1024*E)
// [4460544, 21237760)  ushort Zh[32768][256]  (f16 of Z, [n][d])
// [21237760, 38014976) (unused)
// [38014976, 38015040) int flagCount
// [38015040, 38146112) int flagList[32768]
#define WS_NEED 38146112

typedef __attribute__((ext_vector_type(8))) _Float16 f16x8;
typedef __attribute__((ext_vector_type(4))) float f32x4;

__device__ __forceinline__ ushort f2h(float x) {
    _Float16 h = (_Float16)x;                  // RNE
    return *reinterpret_cast<ushort*>(&h);
}
__device__ __forceinline__ float h2f(ushort u) {
    _Float16 h = *reinterpret_cast<_Float16*>(&u);
    return (float)h;
}

// LDS slot16 index for element (row r, k-group kgi) — bank-spread swizzle.
// Read and stage use the SAME involution (rule: both-sides-or-neither).
__device__ __forceinline__ int swz(int r, int kgi) {
    return (r << 2) + (kgi ^ (r & 3) ^ ((r >> 2) & 3));
}

// ---------------- e2[k]: numpy-exact f32 codebook norms ----------------
__global__ __launch_bounds__(64) void k_e2(const float* __restrict__ E,
                                           float* __restrict__ e2) {
    int k = (blockIdx.x << 6) + threadIdx.x;
    const float* row = E + (size_t)k * DD;
    float half_[2];
#pragma unroll
    for (int h = 0; h < 2; ++h) {
        const float* a = row + (h << 7);
        float r[8];
#pragma unroll
        for (int j = 0; j < 8; ++j) r[j] = __fmul_rn(a[j], a[j]);
        for (int i = 8; i < 128; i += 8) {
#pragma unroll
            for (int j = 0; j < 8; ++j) {
                float x = a[i + j];
                r[j] = __fadd_rn(r[j], __fmul_rn(x, x));
            }
        }
        half_[h] = __fadd_rn(__fadd_rn(__fadd_rn(r[0], r[1]), __fadd_rn(r[2], r[3])),
                             __fadd_rn(__fadd_rn(r[4], r[5]), __fadd_rn(r[6], r[7])));
    }
    e2[k] = __fadd_rn(half_[0], half_[1]);
}

// -- fused: Z transpose tile -> Zh f16 [n][d] + numpy-exact z2 --
__global__ __launch_bounds__(256) void k_prepZ2(const float* __restrict__ Z,
                                                ushort* __restrict__ Zh,
                                                float* __restrict__ z2) {
    __shared__ float zc[16][257];      // 16448 B
    const int g = blockIdx.x;          // 2048 blocks: 16 rows each
    const int b = g >> 6;
    const int hw0 = (g & 63) << 4;
    const int th = threadIdx.x;
    const int n0 = (b << 10) + hw0;

#pragma unroll
    for (int j = 0; j < 16; ++j) {
        int li = (j << 8) + th;        // 0..4095
        int d = li >> 4;
        int hl = li & 15;
        zc[hl][d] = Z[(size_t)((b << 8) + d) * HWN + hw0 + hl];
    }
    __syncthreads();

    // f16 (RNE), [n][d] layout, 32B/thread contiguous
    {
        int r = th >> 4, c = th & 15;
        ushort hs[16];
#pragma unroll
        for (int i = 0; i < 16; ++i) hs[i] = f2h(zc[r][(c << 4) + i]);
        size_t addr = (size_t)(n0 + r) * DD + (c << 4);
        *reinterpret_cast<f16x8*>(&Zh[addr]) = *reinterpret_cast<f16x8*>(&hs[0]);
        *reinterpret_cast<f16x8*>(&Zh[addr + 8]) = *reinterpret_cast<f16x8*>(&hs[8]);
    }

    // z2: numpy pairwise (identical op order to the validated k_z2)
    if (th < 16) {
        const float* rowp = &zc[th][0];
        float half_[2];
#pragma unroll
        for (int h = 0; h < 2; ++h) {
            const float* a = rowp + (h << 7);
            float r[8];
#pragma unroll
            for (int j = 0; j < 8; ++j) r[j] = __fmul_rn(a[j], a[j]);
            for (int i = 8; i < 128; i += 8) {
#pragma unroll
                for (int j = 0; j < 8; ++j) {
                    float x = a[i + j];
                    r[j] = __fadd_rn(r[j], __fmul_rn(x, x));
                }
            }
            half_[h] = __fadd_rn(__fadd_rn(__fadd_rn(r[0], r[1]), __fadd_rn(r[2], r[3])),
                                 __fadd_rn(__fadd_rn(r[4], r[5]), __fadd_rn(r[6], r[7])));
        }
        z2[n0 + th] = __fadd_rn(half_[0], half_[1]);
    }
}

// ---------------- z2 standalone (fallback path only) ----------------
__global__ __launch_bounds__(256) void k_z2(const float* __restrict__ Z,
                                            float* __restrict__ z2) {
    int n = (blockIdx.x << 8) + threadIdx.x;
    int b = n >> 10, hw = n & 1023;
    const float* base = Z + (size_t)(b << 8) * HWN + hw;
    float half_[2];
#pragma unroll
    for (int h = 0; h < 2; ++h) {
        const float* a = base + (size_t)(h << 7) * HWN;
        float r[8];
#pragma unroll
        for (int j = 0; j < 8; ++j) {
            float x = a[(size_t)j * HWN];
            r[j] = __fmul_rn(x, x);
        }
        for (int i = 8; i < 128; i += 8) {
#pragma unroll
            for (int j = 0; j < 8; ++j) {
                float x = a[(size_t)(i + j) * HWN];
                r[j] = __fadd_rn(r[j], __fmul_rn(x, x));
            }
        }
        half_[h] = __fadd_rn(__fadd_rn(__fadd_rn(r[0], r[1]), __fadd_rn(r[2], r[3])),
                             __fadd_rn(__fadd_rn(r[4], r[5]), __fadd_rn(r[6], r[7])));
    }
    z2[n] = __fadd_rn(half_[0], half_[1]);
}

// ------- prep: E -> Eh/El f16 of 1024*E (+ zero flag counter) -------
__global__ __launch_bounds__(256) void k_prepE(const float* __restrict__ E,
                                               ushort* __restrict__ Eh,
                                               ushort* __restrict__ El,
                                               int* __restrict__ flagCount) {
    if (blockIdx.x == 0 && threadIdx.x == 0) *flagCount = 0;
    int i4 = (blockIdx.x << 8) + threadIdx.x;        // 0..65535 float4s
    float4 v = *reinterpret_cast<const float4*>(&E[(size_t)i4 << 2]);
    v.x *= 1024.f; v.y *= 1024.f; v.z *= 1024.f; v.w *= 1024.f;   // exact
    ushort4 h, l;
    h.x = f2h(v.x); l.x = f2h(v.x - h2f(h.x));
    h.y = f2h(v.y); l.y = f2h(v.y - h2f(h.y));
    h.z = f2h(v.z); l.z = f2h(v.z - h2f(h.z));
    h.w = f2h(v.w); l.w = f2h(v.w - h2f(h.w));
    *reinterpret_cast<ushort4*>(&Eh[(size_t)i4 << 2]) = h;
    *reinterpret_cast<ushort4*>(&El[(size_t)i4 << 2]) = l;
}

// --- MFMA distance pass: global_load_lds staging + swizzled layout + 2-phase ---
__device__ __forceinline__ void stage_kc(const ushort* __restrict__ Zh,
                                         const ushort* __restrict__ Eh,
                                         const ushort* __restrict__ El,
                                         ushort* ldsbuf, int n0, int c0, int kc,
                                         int wid, int lane) {
#pragma unroll
    for (int is = 0; is < 6; ++is) {
        const int chunk = wid * 6 + is;    // 0..23 (wave-uniform)
        const int arr = chunk >> 3;        // 0: zh, 1: eh, 2: el
        const int cb8 = chunk & 7;         // chunk within array
        const int s = (cb8 << 6) + lane;   // slot16 this lane fills
        const int r = s >> 2;
        const int kgi = (s & 3) ^ (r & 3) ^ ((r >> 2) & 3);   // inverse swizzle
        const ushort* g;
        if (arr == 0)      g = Zh + (size_t)(n0 + r) * DD;
        else if (arr == 1) g = Eh + (size_t)(c0 + r) * DD;
        else               g = El + (size_t)(c0 + r) * DD;
        g += (kc << 5) + (kgi << 3);
        ushort* l = ldsbuf + arr * 4096 + (cb8 << 9);   // linear dest; HW adds lane*16B
        __builtin_amdgcn_global_load_lds(
            (const __attribute__((address_space(1))) void*)g,
            (__attribute__((address_space(3))) void*)l, 16, 0, 0);
    }
}

__global__ __launch_bounds__(256) void k_dist_mfma(const ushort* __restrict__ Zh,
                                                   const ushort* __restrict__ Eh,
                                                   const ushort* __restrict__ El,
                                                   const float* __restrict__ e2,
                                                   float* __restrict__ part) {
    __shared__ ushort lds[2][3][4096];     // 49152 B: double-buffered {zh, eh, el}
    __shared__ float red[128][2][3];       //  3072 B

    const int B = blockIdx.x;              // 2048 blocks
    const int xcd = B & 7;
    const int j = B >> 3;                  // 0..255
    const int cb = j & 7;
    const int rb = (xcd << 5) + (j >> 3);
    const int n0 = rb << 7, c0 = cb << 7;
    const int th = threadIdx.x;
    const int wid = th >> 6, lane = th & 63;
    const int wr = wid >> 1, wc = wid & 1;
    const int fr = lane & 15, kgi = lane >> 4;

    f32x4 acc[4][4];
#pragma unroll
    for (int i = 0; i < 4; ++i)
#pragma unroll
        for (int jj = 0; jj < 4; ++jj) acc[i][jj] = (f32x4){0.f, 0.f, 0.f, 0.f};

    stage_kc(Zh, Eh, El, &lds[0][0][0], n0, c0, 0, wid, lane);
    __syncthreads();

    int buf = 0;
    for (int kc = 0; kc < 8; ++kc) {
        if (kc < 7)
            stage_kc(Zh, Eh, El, &lds[buf ^ 1][0][0], n0, c0, kc + 1, wid, lane);

        const ushort* zb = &lds[buf][0][0];
        const ushort* ebh = &lds[buf][1][0];
        const ushort* ebl = &lds[buf][2][0];
        f16x8 za[4], ea[4], eb[4];
#pragma unroll
        for (int mi = 0; mi < 4; ++mi) {
            int r = (wr << 6) + (mi << 4) + fr;
            za[mi] = *reinterpret_cast<const f16x8*>(zb + (swz(r, kgi) << 3));
        }
#pragma unroll
        for (int ni = 0; ni < 4; ++ni) {
            int c = (wc << 6) + (ni << 4) + fr;
            ea[ni] = *reinterpret_cast<const f16x8*>(ebh + (swz(c, kgi) << 3));
            eb[ni] = *reinterpret_cast<const f16x8*>(ebl + (swz(c, kgi) << 3));
        }
#pragma unroll
        for (int mi = 0; mi < 4; ++mi)
#pragma unroll
            for (int ni = 0; ni < 4; ++ni) {
                acc[mi][ni] = __builtin_amdgcn_mfma_f32_16x16x32_f16(za[mi], ea[ni], acc[mi][ni], 0, 0, 0);
                acc[mi][ni] = __builtin_amdgcn_mfma_f32_16x16x32_f16(za[mi], eb[ni], acc[mi][ni], 0, 0, 0);
            }
        __syncthreads();               // drains staged loads + frees buf for overwrite
        buf ^= 1;
    }

    float e2v[4];
#pragma unroll
    for (int ni = 0; ni < 4; ++ni) e2v[ni] = e2[c0 + (wc << 6) + (ni << 4) + fr];

#pragma unroll
    for (int mi = 0; mi < 4; ++mi) {
#pragma unroll
        for (int jj = 0; jj < 4; ++jj) {
            float m1 = __builtin_inff(), m2 = __builtin_inff(), bi = 3.4e38f;
#pragma unroll
            for (int ni = 0; ni < 4; ++ni) {
                float s = fmaf(-0x1p-9f, acc[mi][ni][jj], e2v[ni]);  // -2*dot, undo x1024
                float c = (float)(c0 + (wc << 6) + (ni << 4) + fr);
                if (s < m1)      { m2 = m1; m1 = s; bi = c; }
                else if (s < m2) { m2 = s; }
            }
#pragma unroll
            for (int m = 1; m <= 8; m <<= 1) {
                float om1 = __shfl_xor(m1, m);
                float om2 = __shfl_xor(m2, m);
                float obi = __shfl_xor(bi, m);
                if (om1 < m1)       { m2 = fminf(m1, om2); m1 = om1; bi = obi; }
                else if (om1 == m1) { bi = fminf(bi, obi); m2 = m1; }
                else                { m2 = fminf(m2, om1); }
            }
            if (fr == 0) {
                int row = (wr << 6) + (mi << 4) + (kgi << 2) + jj;
                red[row][wc][0] = m1; red[row][wc][1] = m2; red[row][wc][2] = bi;
            }
        }
    }
    __syncthreads();
    if (th < 128) {
        float M1 = red[th][0][0], M2 = red[th][0][1], I = red[th][0][2];
        float v1 = red[th][1][0], v2 = red[th][1][1], vi = red[th][1][2];
        if (v1 < M1)       { M2 = fminf(M1, v2); M1 = v1; I = vi; }
        else if (v1 == M1) { I = fminf(I, vi); M2 = M1; }
        else               { M2 = fminf(M2, v1); }
        size_t p = ((size_t)(n0 + th) * 8 + cb) * 3;
        part[p] = M1; part[p + 1] = M2; part[p + 2] = I;
    }
}

// ------- combine 8 code-slices -> bestIdx + compacted near-tie list -------
__global__ __launch_bounds__(256) void k_combine(const float* __restrict__ part,
                                                 int* __restrict__ bestIdx,
                                                 int* __restrict__ flagList,
                                                 int* __restrict__ flagCount) {
    int n = (blockIdx.x << 8) + threadIdx.x;
    const float* p = part + (size_t)n * 24;
    float M1 = __builtin_inff(), M2 = __builtin_inff(), I = 3.4e38f;
    for (int c = 0; c < 8; ++c) {
        float v1 = p[c * 3], v2 = p[c * 3 + 1], vi = p[c * 3 + 2];
        if (v1 < M1)       { M2 = fminf(M1, v2); M1 = v1; I = vi; }
        else if (v1 == M1) { I = fminf(I, vi); M2 = M1; }
        else               { M2 = fminf(M2, v1); }
    }
    bestIdx[n] = (int)I;
    if (M2 - M1 < MARGIN) {
        int pos = atomicAdd(flagCount, 1);
        flagList[pos] = n;
    }
}

// ---- np-f32-grid re-argmin: 1 row/block, 16 code-groups x 16 lanes, no E staging ----
__global__ __launch_bounds__(256) void k_refine3(const float* __restrict__ Z,
                                                 const float* __restrict__ E,
                                                 const float* __restrict__ e2,
                                                 const float* __restrict__ z2,
                                                 int* __restrict__ bestIdx,
                                                 const int* __restrict__ flagList,
                                                 const int* __restrict__ flagCount) {
    __shared__ float zsh[DD];
    __shared__ float gbv[16];
    __shared__ int gbi[16];
    const int th = threadIdx.x;
    const int g = th >> 4;             // code group 0..15
    const int l = th & 15;             // lane in group
    const int cnt = *flagCount;

    for (int i = blockIdx.x; i < cnt; i += (int)gridDim.x) {
        const int n = flagList[i];
        const int b = n >> 10, hw = n & 1023;
        __syncthreads();               // protect zsh/gbv/gbi from previous row
        if (th < DD) zsh[th] = Z[(size_t)((b << 8) + th) * HWN + hw];
        __syncthreads();
        float zr[16];
#pragma unroll
        for (int jq = 0; jq < 16; ++jq) zr[jq] = zsh[(l << 4) + jq];
        const float z2v = z2[n];
        float gbest = __builtin_inff();
        int bi = 0;

        for (int it = 0; it < 64; ++it) {
            const int c = (it << 4) + g;              // ascending per group
            const float* er = &E[(size_t)c * DD + (l << 4)];
            float4 a0 = *reinterpret_cast<const float4*>(er);
            float4 a1 = *reinterpret_cast<const float4*>(er + 4);
            float4 a2 = *reinterpret_cast<const float4*>(er + 8);
            float4 a3 = *reinterpret_cast<const float4*>(er + 12);
            double s0 = (double)a0.x * zr[0]  + (double)a0.y * zr[1]
                      + (double)a0.z * zr[2]  + (double)a0.w * zr[3];
            double s1 = (double)a1.x * zr[4]  + (double)a1.y * zr[5]
                      + (double)a1.z * zr[6]  + (double)a1.w * zr[7];
            double s2 = (double)a2.x * zr[8]  + (double)a2.y * zr[9]
                      + (double)a2.z * zr[10] + (double)a2.w * zr[11];
            double s3 = (double)a3.x * zr[12] + (double)a3.y * zr[13]
                      + (double)a3.z * zr[14] + (double)a3.w * zr[15];
            double dot = (s0 + s1) + (s2 + s3);
#pragma unroll
            for (int m = 1; m <= 8; m <<= 1) dot += __shfl_xor(dot, m);  // 16-lane sum
            if (l == 0) {
                float cc = (float)dot;
                float t2 = __fmul_rn(2.0f, cc);
                float gg = __fsub_rn(__fadd_rn(z2v, e2[c]), t2);
                if (gg < gbest) { gbest = gg; bi = c; }   // lowest c wins ties
            }
        }
        if (l == 0) { gbv[g] = gbest; gbi[g] = bi; }
        __syncthreads();
        if (th == 0) {
            float best = gbv[0]; int bbi = gbi[0];
            for (int q = 1; q < 16; ++q) {
                float v = gbv[q]; int vi = gbi[q];
                if (v < best || (v == best && vi < bbi)) { best = v; bbi = vi; }
            }
            bestIdx[n] = bbi;
        }
    }
}

// ======== fp32 fallback distance pass (used if ws too small) ========
#define UPD(m1, m2, i1, s, k)                            \
    do {                                                 \
        if ((s) < (m1)) { m2 = m1; m1 = (s); i1 = (k); } \
        else if ((s) < (m2)) { m2 = (s); }               \
    } while (0)

#define FMAJ(j, EV, C)                                   \
    acc[0][j] = fmaf(z4.x, EV.C, acc[0][j]);             \
    acc[1][j] = fmaf(z4.y, EV.C, acc[1][j]);             \
    acc[2][j] = fmaf(z4.z, EV.C, acc[2][j]);             \
    acc[3][j] = fmaf(z4.w, EV.C, acc[3][j]);

#define UROUND(u, C)                                                          \
    {                                                                         \
        float4 z4 = *reinterpret_cast<const float4*>(&zs[dq + u][ty4]);       \
        FMAJ(0, e0, C) FMAJ(1, e1, C) FMAJ(2, e2v, C) FMAJ(3, e3, C)          \
        FMAJ(4, e4, C) FMAJ(5, e5, C) FMAJ(6, e6, C) FMAJ(7, e7, C)           \
    }

__global__ __launch_bounds__(256, 3) void k_dist_f32(const float* __restrict__ Z,
                                                     const float* __restrict__ E,
                                                     const float* __restrict__ e2,
                                                     int* __restrict__ bestIdx) {
    __shared__ float zs[64][68];
    __shared__ float es[128][68];
    const int th = threadIdx.x;
    const int n0 = blockIdx.x << 6;
    const int b = n0 >> 10;
    const int hw0 = n0 & 1023;
    const int tx = th & 15;
    const int ty = th >> 4;
    const int ty4 = ty << 2;
    float m1[4], m2[4];
    int idx[4];
#pragma unroll
    for (int i = 0; i < 4; ++i) { m1[i] = __builtin_inff(); m2[i] = __builtin_inff(); idx[i] = 0; }
    for (int ct = 0; ct < 8; ++ct) {
        float acc[4][8];
#pragma unroll
        for (int i = 0; i < 4; ++i)
#pragma unroll
            for (int j = 0; j < 8; ++j) acc[i][j] = 0.f;
        for (int dc = 0; dc < 4; ++dc) {
            __syncthreads();
#pragma unroll
            for (int j = 0; j < 4; ++j) {
                int i4 = (j << 8) + th;
                int dd = i4 >> 4;
                int rr = (i4 & 15) << 2;
                *reinterpret_cast<float4*>(&zs[dd][rr]) =
                    *reinterpret_cast<const float4*>(
                        &Z[(size_t)((b << 8) + (dc << 6) + dd) * HWN + hw0 + rr]);
            }
#pragma unroll
            for (int j = 0; j < 8; ++j) {
                int i4 = (j << 8) + th;
                int c = i4 >> 4;
                int d4 = (i4 & 15) << 2;
                *reinterpret_cast<float4*>(&es[c][d4]) =
                    *reinterpret_cast<const float4*>(
                        &E[(size_t)((ct << 7) + c) * DD + (dc << 6) + d4]);
            }
            __syncthreads();
#pragma unroll
            for (int dq = 0; dq < 64; dq += 4) {
                float4 e0 = *reinterpret_cast<const float4*>(&es[tx][dq]);
                float4 e1 = *reinterpret_cast<const float4*>(&es[tx + 16][dq]);
                float4 e2v = *reinterpret_cast<const float4*>(&es[tx + 32][dq]);
                float4 e3 = *reinterpret_cast<const float4*>(&es[tx + 48][dq]);
                float4 e4 = *reinterpret_cast<const float4*>(&es[tx + 64][dq]);
                float4 e5 = *reinterpret_cast<const float4*>(&es[tx + 80][dq]);
                float4 e6 = *reinterpret_cast<const float4*>(&es[tx + 96][dq]);
                float4 e7 = *reinterpret_cast<const float4*>(&es[tx + 112][dq]);
                UROUND(0, x)
                UROUND(1, y)
                UROUND(2, z)
                UROUND(3, w)
            }
        }
#pragma unroll
        for (int j = 0; j < 8; ++j) {
            int c = (ct << 7) + tx + (j << 4);
            float en = e2[c];
#pragma unroll
            for (int i = 0; i < 4; ++i) {
                float s = fmaf(-2.f, acc[i][j], en);
                UPD(m1[i], m2[i], idx[i], s, c);
            }
        }
    }
    __syncthreads();
    float* red = &es[0][0];
#pragma unroll
    for (int i = 0; i < 4; ++i) {
        int r = ty4 + i;
        int base = ((r << 4) + tx) * 3;
        red[base] = m1[i]; red[base + 1] = m2[i]; red[base + 2] = (float)idx[i];
    }
    __syncthreads();
    if (th < 64) {
        float M1 = __builtin_inff(), M2 = __builtin_inff(), I = 3.4e38f;
        for (int t = 0; t < 16; ++t) {
            int base = ((th << 4) + t) * 3;
            float v1 = red[base], v2 = red[base + 1], vi = red[base + 2];
            if (v1 < M1)       { M2 = fminf(M1, v2); M1 = v1; I = vi; }
            else if (v1 == M1) { I = fminf(I, vi); M2 = fminf(M2, v1); M2 = fminf(M2, v2); }
            else               { M2 = fminf(M2, v1); }
        }
        int id = (int)I;
        bestIdx[n0 + th] = (M2 - M1 < MARGIN) ? (id | FLAGBIT) : id;
    }
}

// -------- fallback-path refine (FLAGBIT scan, unchanged semantics) --------
__global__ __launch_bounds__(64) void k_refine(const float* __restrict__ Z,
                                               const float* __restrict__ E,
                                               const float* __restrict__ e2,
                                               const float* __restrict__ z2,
                                               int* __restrict__ bestIdx) {
    __shared__ float zr[DD];
    const int l = threadIdx.x;
    for (int i = 0; i < 16; ++i) {
        int n = (blockIdx.x << 4) + i;
        if (!(bestIdx[n] & FLAGBIT)) continue;
        int b = n >> 10, hw = n & 1023;
        __syncthreads();
#pragma unroll
        for (int j = 0; j < 4; ++j)
            zr[(l << 2) + j] = Z[(size_t)((b << 8) + (l << 2) + j) * HWN + hw];
        __syncthreads();
        const float z2v = z2[n];
        float gbest = __builtin_inff();
        int bi = KK;
        for (int kk = 0; kk < 16; ++kk) {
            int k = (kk << 6) + l;
            double dot = 0.0;
            for (int d = 0; d < DD; d += 4) {
                float4 e4 = *reinterpret_cast<const float4*>(&E[(size_t)k * DD + d]);
                dot += (double)e4.x * zr[d]     + (double)e4.y * zr[d + 1]
                     + (double)e4.z * zr[d + 2] + (double)e4.w * zr[d + 3];
            }
            float c = (float)dot;
            float t = __fmul_rn(2.0f, c);
            float gg = __fsub_rn(__fadd_rn(z2v, e2[k]), t);
            if (gg < gbest) { gbest = gg; bi = k; }
        }
#pragma unroll
        for (int off = 32; off > 0; off >>= 1) {
            float og = __shfl_down(gbest, off);
            int oi = __shfl_down(bi, off);
            if (og < gbest || (og == gbest && oi < bi)) { gbest = og; bi = oi; }
        }
        if (l == 0) bestIdx[n] = bi;
    }
}

// -------- outputs: idx, loss (NHWC), z_q (NCHW) --------
__global__ __launch_bounds__(256) void k_out(const float* __restrict__ Z,
                                             const float* __restrict__ E,
                                             const int* __restrict__ bestIdx,
                                             float* __restrict__ out) {
    __shared__ float zc[64][68];
    __shared__ int idxs[64];
    const int th = threadIdx.x;
    const int n0 = blockIdx.x << 6;
    const int b = n0 >> 10;
    const int hw0 = n0 & 1023;

    if (th < 64) {
        int id = bestIdx[n0 + th] & 1023;
        idxs[th] = id;
        out[IDX_OFF + n0 + th] = (float)id;
    }
    __syncthreads();

    for (int dc = 0; dc < 4; ++dc) {
        __syncthreads();
#pragma unroll
        for (int j = 0; j < 16; ++j) {
            int li = (j << 8) + th;
            int dd = li >> 6;
            int r = li & 63;
            zc[r][dd] = Z[(size_t)((b << 8) + (dc << 6) + dd) * HWN + hw0 + r];
        }
        __syncthreads();
#pragma unroll
        for (int j = 0; j < 4; ++j) {
            int i4 = (j << 8) + th;
            int r = i4 >> 4;
            int f = (i4 & 15) << 2;
            float4 e4 = *reinterpret_cast<const float4*>(
                &E[(size_t)idxs[r] * DD + (dc << 6) + f]);
            float4 z4 = *reinterpret_cast<const float4*>(&zc[r][f]);
            float4 o;
            o.x = (e4.x - z4.x) * (e4.x - z4.x);
            o.y = (e4.y - z4.y) * (e4.y - z4.y);
            o.z = (e4.z - z4.z) * (e4.z - z4.z);
            o.w = (e4.w - z4.w) * (e4.w - z4.w);
            *reinterpret_cast<float4*>(
                &out[LOSS_OFF + (size_t)(n0 + r) * DD + (dc << 6) + f]) = o;
        }
#pragma unroll
        for (int j = 0; j < 16; ++j) {
            int li = (j << 8) + th;
            int dd = li >> 6;
            int r = li & 63;
            out[ZQ_OFF + (size_t)((b << 8) + (dc << 6) + dd) * HWN + hw0 + r] =
                E[(size_t)idxs[r] * DD + (dc << 6) + dd];
        }
    }
}

extern "C" void kernel_launch(void* const* d_in, const int* in_sizes, int n_in,
                              void* d_out, int out_size, void* d_ws, size_t ws_size,
                              hipStream_t stream) {
    const float* Z = (const float*)d_in[0];           // [32,256,32,32] f32
    const float* E = (const float*)d_in[1];           // [1024,256] f32
    float* out = (float*)d_out;
    char* ws = (char*)d_ws;
    float* e2 = (float*)ws;
    float* z2 = (float*)(ws + 4096);
    int* bestIdx = (int*)(ws + 135168);

    k_e2<<<KK / 64, 64, 0, stream>>>(E, e2);

    if (ws_size >= WS_NEED) {
        float* part = (float*)(ws + 266240);
        ushort* Eh = (ushort*)(ws + 3411968);
        ushort* El = (ushort*)(ws + 3936256);
        ushort* Zh = (ushort*)(ws + 4460544);
        int* flagCount = (int*)(ws + 38014976);
        int* flagList = (int*)(ws + 38015040);
        k_prepE<<<256, 256, 0, stream>>>(E, Eh, El, flagCount);
        k_prepZ2<<<2048, 256, 0, stream>>>(Z, Zh, z2);
        k_dist_mfma<<<2048, 256, 0, stream>>>(Zh, Eh, El, e2, part);
        k_combine<<<NN / 256, 256, 0, stream>>>(part, bestIdx, flagList, flagCount);
        k_refine3<<<2048, 256, 0, stream>>>(Z, E, e2, z2, bestIdx, flagList, flagCount);
    } else {
        k_z2<<<NN / 256, 256, 0, stream>>>(Z, z2);
        k_dist_f32<<<NN / 64, 256, 0, stream>>>(Z, E, e2, bestIdx);
        k_refine<<<NN / 16, 64, 0, stream>>>(Z, E, e2, z2, bestIdx);
    }

    k_out<<<NN / 64, 256, 0, stream>>>(Z, E, bestIdx, out);
}

// Round 15
// 201.508 us; speedup vs baseline: 1.6309x; 1.0043x over previous
//
#include <hip/hip_runtime.h>

#define DD 256
#define HWN 1024
#define NN 32768
#define KK 1024
#define MARGIN 1e-4f
#define FLAGBIT (1 << 30)

// f32-element offsets into d_out (out_size = 16809984 floats):
#define ZQ_OFF   0          // z_q   [32,256,32,32]
#define IDX_OFF  8388608    // idx   [32768]
#define LOSS_OFF 8421376    // loss  [32,32,32,256] (NHWC)

// ws layout (MFMA path needs WS_NEED bytes; else fp32 fallback):
// [0, 4096)            float e2[1024]
// [4096, 135168)       float z2[32768]
// [135168, 266240)     int   bestIdx[32768]
// [266240, 3411968)    float part[32768][8][3]
// [3411968, 3936256)   ushort Eh[1024][256]   (f16 of 1024*E)
// [3936256, 4460544)   ushort El[1024][256]   (f16 residual of 1024*E)
// [4460544, 21237760)  ushort Zh[32768][256]  (f16 of Z, [n][d])
// [21237760, 38014976) (unused)
// [38014976, 38015040) int flagCount
// [38015040, 38146112) int flagList[32768]
#define WS_NEED 38146112

typedef __attribute__((ext_vector_type(8))) _Float16 f16x8;
typedef __attribute__((ext_vector_type(4))) float f32x4;

__device__ __forceinline__ ushort f2h(float x) {
    _Float16 h = (_Float16)x;                  // RNE
    return *reinterpret_cast<ushort*>(&h);
}
__device__ __forceinline__ float h2f(ushort u) {
    _Float16 h = *reinterpret_cast<_Float16*>(&u);
    return (float)h;
}

// LDS slot16 index for element (row r, k-group kgi) — bank-spread swizzle.
// Read and stage use the SAME involution (rule: both-sides-or-neither).
__device__ __forceinline__ int swz(int r, int kgi) {
    return (r << 2) + (kgi ^ (r & 3) ^ ((r >> 2) & 3));
}

// ---------------- e2[k]: numpy-exact f32 codebook norms ----------------
__global__ __launch_bounds__(64) void k_e2(const float* __restrict__ E,
                                           float* __restrict__ e2) {
    int k = (blockIdx.x << 6) + threadIdx.x;
    const float* row = E + (size_t)k * DD;
    float half_[2];
#pragma unroll
    for (int h = 0; h < 2; ++h) {
        const float* a = row + (h << 7);
        float r[8];
#pragma unroll
        for (int j = 0; j < 8; ++j) r[j] = __fmul_rn(a[j], a[j]);
        for (int i = 8; i < 128; i += 8) {
#pragma unroll
            for (int j = 0; j < 8; ++j) {
                float x = a[i + j];
                r[j] = __fadd_rn(r[j], __fmul_rn(x, x));
            }
        }
        half_[h] = __fadd_rn(__fadd_rn(__fadd_rn(r[0], r[1]), __fadd_rn(r[2], r[3])),
                             __fadd_rn(__fadd_rn(r[4], r[5]), __fadd_rn(r[6], r[7])));
    }
    e2[k] = __fadd_rn(half_[0], half_[1]);
}

// -- fused: Z transpose tile -> Zh f16 [n][d] + numpy-exact z2 --
__global__ __launch_bounds__(256) void k_prepZ2(const float* __restrict__ Z,
                                                ushort* __restrict__ Zh,
                                                float* __restrict__ z2) {
    __shared__ float zc[16][257];      // 16448 B
    const int g = blockIdx.x;          // 2048 blocks: 16 rows each
    const int b = g >> 6;
    const int hw0 = (g & 63) << 4;
    const int th = threadIdx.x;
    const int n0 = (b << 10) + hw0;

#pragma unroll
    for (int j = 0; j < 16; ++j) {
        int li = (j << 8) + th;        // 0..4095
        int d = li >> 4;
        int hl = li & 15;
        zc[hl][d] = Z[(size_t)((b << 8) + d) * HWN + hw0 + hl];
    }
    __syncthreads();

    // f16 (RNE), [n][d] layout, 32B/thread contiguous
    {
        int r = th >> 4, c = th & 15;
        ushort hs[16];
#pragma unroll
        for (int i = 0; i < 16; ++i) hs[i] = f2h(zc[r][(c << 4) + i]);
        size_t addr = (size_t)(n0 + r) * DD + (c << 4);
        *reinterpret_cast<f16x8*>(&Zh[addr]) = *reinterpret_cast<f16x8*>(&hs[0]);
        *reinterpret_cast<f16x8*>(&Zh[addr + 8]) = *reinterpret_cast<f16x8*>(&hs[8]);
    }

    // z2: numpy pairwise (identical op order to the validated k_z2)
    if (th < 16) {
        const float* rowp = &zc[th][0];
        float half_[2];
#pragma unroll
        for (int h = 0; h < 2; ++h) {
            const float* a = rowp + (h << 7);
            float r[8];
#pragma unroll
            for (int j = 0; j < 8; ++j) r[j] = __fmul_rn(a[j], a[j]);
            for (int i = 8; i < 128; i += 8) {
#pragma unroll
                for (int j = 0; j < 8; ++j) {
                    float x = a[i + j];
                    r[j] = __fadd_rn(r[j], __fmul_rn(x, x));
                }
            }
            half_[h] = __fadd_rn(__fadd_rn(__fadd_rn(r[0], r[1]), __fadd_rn(r[2], r[3])),
                                 __fadd_rn(__fadd_rn(r[4], r[5]), __fadd_rn(r[6], r[7])));
        }
        z2[n0 + th] = __fadd_rn(half_[0], half_[1]);
    }
}

// ---------------- z2 standalone (fallback path only) ----------------
__global__ __launch_bounds__(256) void k_z2(const float* __restrict__ Z,
                                            float* __restrict__ z2) {
    int n = (blockIdx.x << 8) + threadIdx.x;
    int b = n >> 10, hw = n & 1023;
    const float* base = Z + (size_t)(b << 8) * HWN + hw;
    float half_[2];
#pragma unroll
    for (int h = 0; h < 2; ++h) {
        const float* a = base + (size_t)(h << 7) * HWN;
        float r[8];
#pragma unroll
        for (int j = 0; j < 8; ++j) {
            float x = a[(size_t)j * HWN];
            r[j] = __fmul_rn(x, x);
        }
        for (int i = 8; i < 128; i += 8) {
#pragma unroll
            for (int j = 0; j < 8; ++j) {
                float x = a[(size_t)(i + j) * HWN];
                r[j] = __fadd_rn(r[j], __fmul_rn(x, x));
            }
        }
        half_[h] = __fadd_rn(__fadd_rn(__fadd_rn(r[0], r[1]), __fadd_rn(r[2], r[3])),
                             __fadd_rn(__fadd_rn(r[4], r[5]), __fadd_rn(r[6], r[7])));
    }
    z2[n] = __fadd_rn(half_[0], half_[1]);
}

// ------- prep: E -> Eh/El f16 of 1024*E (+ zero flag counter) -------
__global__ __launch_bounds__(256) void k_prepE(const float* __restrict__ E,
                                               ushort* __restrict__ Eh,
                                               ushort* __restrict__ El,
                                               int* __restrict__ flagCount) {
    if (blockIdx.x == 0 && threadIdx.x == 0) *flagCount = 0;
    int i4 = (blockIdx.x << 8) + threadIdx.x;        // 0..65535 float4s
    float4 v = *reinterpret_cast<const float4*>(&E[(size_t)i4 << 2]);
    v.x *= 1024.f; v.y *= 1024.f; v.z *= 1024.f; v.w *= 1024.f;   // exact
    ushort4 h, l;
    h.x = f2h(v.x); l.x = f2h(v.x - h2f(h.x));
    h.y = f2h(v.y); l.y = f2h(v.y - h2f(h.y));
    h.z = f2h(v.z); l.z = f2h(v.z - h2f(h.z));
    h.w = f2h(v.w); l.w = f2h(v.w - h2f(h.w));
    *reinterpret_cast<ushort4*>(&Eh[(size_t)i4 << 2]) = h;
    *reinterpret_cast<ushort4*>(&El[(size_t)i4 << 2]) = l;
}

// --- MFMA distance pass: global_load_lds + swizzle + counted-vmcnt pipeline ---
__device__ __forceinline__ void stage_kc(const ushort* __restrict__ Zh,
                                         const ushort* __restrict__ Eh,
                                         const ushort* __restrict__ El,
                                         ushort* ldsbuf, int n0, int c0, int kc,
                                         int wid, int lane) {
#pragma unroll
    for (int is = 0; is < 6; ++is) {
        const int chunk = wid * 6 + is;    // 0..23 (wave-uniform)
        const int arr = chunk >> 3;        // 0: zh, 1: eh, 2: el
        const int cb8 = chunk & 7;         // chunk within array
        const int s = (cb8 << 6) + lane;   // slot16 this lane fills
        const int r = s >> 2;
        const int kgi = (s & 3) ^ (r & 3) ^ ((r >> 2) & 3);   // inverse swizzle
        const ushort* g;
        if (arr == 0)      g = Zh + (size_t)(n0 + r) * DD;
        else if (arr == 1) g = Eh + (size_t)(c0 + r) * DD;
        else               g = El + (size_t)(c0 + r) * DD;
        g += (kc << 5) + (kgi << 3);
        ushort* l = ldsbuf + arr * 4096 + (cb8 << 9);   // linear dest; HW adds lane*16B
        __builtin_amdgcn_global_load_lds(
            (const __attribute__((address_space(1))) void*)g,
            (__attribute__((address_space(3))) void*)l, 16, 0, 0);
    }
}

__global__ __launch_bounds__(256) void k_dist_mfma(const ushort* __restrict__ Zh,
                                                   const ushort* __restrict__ Eh,
                                                   const ushort* __restrict__ El,
                                                   const float* __restrict__ e2,
                                                   float* __restrict__ part) {
    __shared__ ushort lds[2][3][4096];     // 49152 B: double-buffered {zh, eh, el}
    __shared__ float red[128][2][3];       //  3072 B

    const int B = blockIdx.x;              // 2048 blocks
    const int xcd = B & 7;
    const int j = B >> 3;                  // 0..255
    const int cb = j & 7;
    const int rb = (xcd << 5) + (j >> 3);
    const int n0 = rb << 7, c0 = cb << 7;
    const int th = threadIdx.x;
    const int wid = th >> 6, lane = th & 63;
    const int wr = wid >> 1, wc = wid & 1;
    const int fr = lane & 15, kgi = lane >> 4;

    f32x4 acc[4][4];
#pragma unroll
    for (int i = 0; i < 4; ++i)
#pragma unroll
        for (int jj = 0; jj < 4; ++jj) acc[i][jj] = (f32x4){0.f, 0.f, 0.f, 0.f};

    stage_kc(Zh, Eh, El, &lds[0][0][0], n0, c0, 0, wid, lane);

    for (int kc = 0; kc < 8; ++kc) {
        // barrier A: previous iter's LDS reads done before overwriting that buffer
        __builtin_amdgcn_s_barrier();
        if (kc < 7) {
            stage_kc(Zh, Eh, El, &lds[(kc + 1) & 1][0][0], n0, c0, kc + 1, wid, lane);
            // wait only MY stage(kc) loads (6 newer stay in flight across barrier)
            asm volatile("s_waitcnt vmcnt(6)" ::: "memory");
        } else {
            asm volatile("s_waitcnt vmcnt(0)" ::: "memory");
        }
        // barrier B: ALL waves' stage(kc) loads have landed
        __builtin_amdgcn_s_barrier();

        const ushort* zb  = &lds[kc & 1][0][0];
        const ushort* ebh = &lds[kc & 1][1][0];
        const ushort* ebl = &lds[kc & 1][2][0];
        f16x8 za[4], ea[4], eb[4];
#pragma unroll
        for (int mi = 0; mi < 4; ++mi) {
            int r = (wr << 6) + (mi << 4) + fr;
            za[mi] = *reinterpret_cast<const f16x8*>(zb + (swz(r, kgi) << 3));
        }
#pragma unroll
        for (int ni = 0; ni < 4; ++ni) {
            int c = (wc << 6) + (ni << 4) + fr;
            ea[ni] = *reinterpret_cast<const f16x8*>(ebh + (swz(c, kgi) << 3));
            eb[ni] = *reinterpret_cast<const f16x8*>(ebl + (swz(c, kgi) << 3));
        }
#pragma unroll
        for (int mi = 0; mi < 4; ++mi)
#pragma unroll
            for (int ni = 0; ni < 4; ++ni) {
                acc[mi][ni] = __builtin_amdgcn_mfma_f32_16x16x32_f16(za[mi], ea[ni], acc[mi][ni], 0, 0, 0);
                acc[mi][ni] = __builtin_amdgcn_mfma_f32_16x16x32_f16(za[mi], eb[ni], acc[mi][ni], 0, 0, 0);
            }
        // ds_reads are consumed (lgkmcnt) before this wave reaches next barrier A
    }

    float e2v[4];
#pragma unroll
    for (int ni = 0; ni < 4; ++ni) e2v[ni] = e2[c0 + (wc << 6) + (ni << 4) + fr];

#pragma unroll
    for (int mi = 0; mi < 4; ++mi) {
#pragma unroll
        for (int jj = 0; jj < 4; ++jj) {
            float m1 = __builtin_inff(), m2 = __builtin_inff(), bi = 3.4e38f;
#pragma unroll
            for (int ni = 0; ni < 4; ++ni) {
                float s = fmaf(-0x1p-9f, acc[mi][ni][jj], e2v[ni]);  // -2*dot, undo x1024
                float c = (float)(c0 + (wc << 6) + (ni << 4) + fr);
                if (s < m1)      { m2 = m1; m1 = s; bi = c; }
                else if (s < m2) { m2 = s; }
            }
#pragma unroll
            for (int m = 1; m <= 8; m <<= 1) {
                float om1 = __shfl_xor(m1, m);
                float om2 = __shfl_xor(m2, m);
                float obi = __shfl_xor(bi, m);
                if (om1 < m1)       { m2 = fminf(m1, om2); m1 = om1; bi = obi; }
                else if (om1 == m1) { bi = fminf(bi, obi); m2 = m1; }
                else                { m2 = fminf(m2, om1); }
            }
            if (fr == 0) {
                int row = (wr << 6) + (mi << 4) + (kgi << 2) + jj;
                red[row][wc][0] = m1; red[row][wc][1] = m2; red[row][wc][2] = bi;
            }
        }
    }
    __syncthreads();
    if (th < 128) {
        float M1 = red[th][0][0], M2 = red[th][0][1], I = red[th][0][2];
        float v1 = red[th][1][0], v2 = red[th][1][1], vi = red[th][1][2];
        if (v1 < M1)       { M2 = fminf(M1, v2); M1 = v1; I = vi; }
        else if (v1 == M1) { I = fminf(I, vi); M2 = M1; }
        else               { M2 = fminf(M2, v1); }
        size_t p = ((size_t)(n0 + th) * 8 + cb) * 3;
        part[p] = M1; part[p + 1] = M2; part[p + 2] = I;
    }
}

// ------- combine 8 code-slices -> bestIdx + compacted near-tie list -------
__global__ __launch_bounds__(256) void k_combine(const float* __restrict__ part,
                                                 int* __restrict__ bestIdx,
                                                 int* __restrict__ flagList,
                                                 int* __restrict__ flagCount) {
    int n = (blockIdx.x << 8) + threadIdx.x;
    const float* p = part + (size_t)n * 24;
    float M1 = __builtin_inff(), M2 = __builtin_inff(), I = 3.4e38f;
    for (int c = 0; c < 8; ++c) {
        float v1 = p[c * 3], v2 = p[c * 3 + 1], vi = p[c * 3 + 2];
        if (v1 < M1)       { M2 = fminf(M1, v2); M1 = v1; I = vi; }
        else if (v1 == M1) { I = fminf(I, vi); M2 = M1; }
        else               { M2 = fminf(M2, v1); }
    }
    bestIdx[n] = (int)I;
    if (M2 - M1 < MARGIN) {
        int pos = atomicAdd(flagCount, 1);
        flagList[pos] = n;
    }
}

// ---- np-f32-grid re-argmin: 1 row/block, 16 code-groups x 16 lanes, no E staging ----
__global__ __launch_bounds__(256) void k_refine3(const float* __restrict__ Z,
                                                 const float* __restrict__ E,
                                                 const float* __restrict__ e2,
                                                 const float* __restrict__ z2,
                                                 int* __restrict__ bestIdx,
                                                 const int* __restrict__ flagList,
                                                 const int* __restrict__ flagCount) {
    __shared__ float zsh[DD];
    __shared__ float gbv[16];
    __shared__ int gbi[16];
    const int th = threadIdx.x;
    const int g = th >> 4;             // code group 0..15
    const int l = th & 15;             // lane in group
    const int cnt = *flagCount;

    for (int i = blockIdx.x; i < cnt; i += (int)gridDim.x) {
        const int n = flagList[i];
        const int b = n >> 10, hw = n & 1023;
        __syncthreads();               // protect zsh/gbv/gbi from previous row
        if (th < DD) zsh[th] = Z[(size_t)((b << 8) + th) * HWN + hw];
        __syncthreads();
        float zr[16];
#pragma unroll
        for (int jq = 0; jq < 16; ++jq) zr[jq] = zsh[(l << 4) + jq];
        const float z2v = z2[n];
        float gbest = __builtin_inff();
        int bi = 0;

        for (int it = 0; it < 64; ++it) {
            const int c = (it << 4) + g;              // ascending per group
            const float* er = &E[(size_t)c * DD + (l << 4)];
            float4 a0 = *reinterpret_cast<const float4*>(er);
            float4 a1 = *reinterpret_cast<const float4*>(er + 4);
            float4 a2 = *reinterpret_cast<const float4*>(er + 8);
            float4 a3 = *reinterpret_cast<const float4*>(er + 12);
            double s0 = (double)a0.x * zr[0]  + (double)a0.y * zr[1]
                      + (double)a0.z * zr[2]  + (double)a0.w * zr[3];
            double s1 = (double)a1.x * zr[4]  + (double)a1.y * zr[5]
                      + (double)a1.z * zr[6]  + (double)a1.w * zr[7];
            double s2 = (double)a2.x * zr[8]  + (double)a2.y * zr[9]
                      + (double)a2.z * zr[10] + (double)a2.w * zr[11];
            double s3 = (double)a3.x * zr[12] + (double)a3.y * zr[13]
                      + (double)a3.z * zr[14] + (double)a3.w * zr[15];
            double dot = (s0 + s1) + (s2 + s3);
#pragma unroll
            for (int m = 1; m <= 8; m <<= 1) dot += __shfl_xor(dot, m);  // 16-lane sum
            if (l == 0) {
                float cc = (float)dot;
                float t2 = __fmul_rn(2.0f, cc);
                float gg = __fsub_rn(__fadd_rn(z2v, e2[c]), t2);
                if (gg < gbest) { gbest = gg; bi = c; }   // lowest c wins ties
            }
        }
        if (l == 0) { gbv[g] = gbest; gbi[g] = bi; }
        __syncthreads();
        if (th == 0) {
            float best = gbv[0]; int bbi = gbi[0];
            for (int q = 1; q < 16; ++q) {
                float v = gbv[q]; int vi = gbi[q];
                if (v < best || (v == best && vi < bbi)) { best = v; bbi = vi; }
            }
            bestIdx[n] = bbi;
        }
    }
}

// ======== fp32 fallback distance pass (used if ws too small) ========
#define UPD(m1, m2, i1, s, k)                            \
    do {                                                 \
        if ((s) < (m1)) { m2 = m1; m1 = (s); i1 = (k); } \
        else if ((s) < (m2)) { m2 = (s); }               \
    } while (0)

#define FMAJ(j, EV, C)                                   \
    acc[0][j] = fmaf(z4.x, EV.C, acc[0][j]);             \
    acc[1][j] = fmaf(z4.y, EV.C, acc[1][j]);             \
    acc[2][j] = fmaf(z4.z, EV.C, acc[2][j]);             \
    acc[3][j] = fmaf(z4.w, EV.C, acc[3][j]);

#define UROUND(u, C)                                                          \
    {                                                                         \
        float4 z4 = *reinterpret_cast<const float4*>(&zs[dq + u][ty4]);       \
        FMAJ(0, e0, C) FMAJ(1, e1, C) FMAJ(2, e2v, C) FMAJ(3, e3, C)          \
        FMAJ(4, e4, C) FMAJ(5, e5, C) FMAJ(6, e6, C) FMAJ(7, e7, C)           \
    }

__global__ __launch_bounds__(256, 3) void k_dist_f32(const float* __restrict__ Z,
                                                     const float* __restrict__ E,
                                                     const float* __restrict__ e2,
                                                     int* __restrict__ bestIdx) {
    __shared__ float zs[64][68];
    __shared__ float es[128][68];
    const int th = threadIdx.x;
    const int n0 = blockIdx.x << 6;
    const int b = n0 >> 10;
    const int hw0 = n0 & 1023;
    const int tx = th & 15;
    const int ty = th >> 4;
    const int ty4 = ty << 2;
    float m1[4], m2[4];
    int idx[4];
#pragma unroll
    for (int i = 0; i < 4; ++i) { m1[i] = __builtin_inff(); m2[i] = __builtin_inff(); idx[i] = 0; }
    for (int ct = 0; ct < 8; ++ct) {
        float acc[4][8];
#pragma unroll
        for (int i = 0; i < 4; ++i)
#pragma unroll
            for (int j = 0; j < 8; ++j) acc[i][j] = 0.f;
        for (int dc = 0; dc < 4; ++dc) {
            __syncthreads();
#pragma unroll
            for (int j = 0; j < 4; ++j) {
                int i4 = (j << 8) + th;
                int dd = i4 >> 4;
                int rr = (i4 & 15) << 2;
                *reinterpret_cast<float4*>(&zs[dd][rr]) =
                    *reinterpret_cast<const float4*>(
                        &Z[(size_t)((b << 8) + (dc << 6) + dd) * HWN + hw0 + rr]);
            }
#pragma unroll
            for (int j = 0; j < 8; ++j) {
                int i4 = (j << 8) + th;
                int c = i4 >> 4;
                int d4 = (i4 & 15) << 2;
                *reinterpret_cast<float4*>(&es[c][d4]) =
                    *reinterpret_cast<const float4*>(
                        &E[(size_t)((ct << 7) + c) * DD + (dc << 6) + d4]);
            }
            __syncthreads();
#pragma unroll
            for (int dq = 0; dq < 64; dq += 4) {
                float4 e0 = *reinterpret_cast<const float4*>(&es[tx][dq]);
                float4 e1 = *reinterpret_cast<const float4*>(&es[tx + 16][dq]);
                float4 e2v = *reinterpret_cast<const float4*>(&es[tx + 32][dq]);
                float4 e3 = *reinterpret_cast<const float4*>(&es[tx + 48][dq]);
                float4 e4 = *reinterpret_cast<const float4*>(&es[tx + 64][dq]);
                float4 e5 = *reinterpret_cast<const float4*>(&es[tx + 80][dq]);
                float4 e6 = *reinterpret_cast<const float4*>(&es[tx + 96][dq]);
                float4 e7 = *reinterpret_cast<const float4*>(&es[tx + 112][dq]);
                UROUND(0, x)
                UROUND(1, y)
                UROUND(2, z)
                UROUND(3, w)
            }
        }
#pragma unroll
        for (int j = 0; j < 8; ++j) {
            int c = (ct << 7) + tx + (j << 4);
            float en = e2[c];
#pragma unroll
            for (int i = 0; i < 4; ++i) {
                float s = fmaf(-2.f, acc[i][j], en);
                UPD(m1[i], m2[i], idx[i], s, c);
            }
        }
    }
    __syncthreads();
    float* red = &es[0][0];
#pragma unroll
    for (int i = 0; i < 4; ++i) {
        int r = ty4 + i;
        int base = ((r << 4) + tx) * 3;
        red[base] = m1[i]; red[base + 1] = m2[i]; red[base + 2] = (float)idx[i];
    }
    __syncthreads();
    if (th < 64) {
        float M1 = __builtin_inff(), M2 = __builtin_inff(), I = 3.4e38f;
        for (int t = 0; t < 16; ++t) {
            int base = ((th << 4) + t) * 3;
            float v1 = red[base], v2 = red[base + 1], vi = red[base + 2];
            if (v1 < M1)       { M2 = fminf(M1, v2); M1 = v1; I = vi; }
            else if (v1 == M1) { I = fminf(I, vi); M2 = fminf(M2, v1); M2 = fminf(M2, v2); }
            else               { M2 = fminf(M2, v1); }
        }
        int id = (int)I;
        bestIdx[n0 + th] = (M2 - M1 < MARGIN) ? (id | FLAGBIT) : id;
    }
}

// -------- fallback-path refine (FLAGBIT scan, unchanged semantics) --------
__global__ __launch_bounds__(64) void k_refine(const float* __restrict__ Z,
                                               const float* __restrict__ E,
                                               const float* __restrict__ e2,
                                               const float* __restrict__ z2,
                                               int* __restrict__ bestIdx) {
    __shared__ float zr[DD];
    const int l = threadIdx.x;
    for (int i = 0; i < 16; ++i) {
        int n = (blockIdx.x << 4) + i;
        if (!(bestIdx[n] & FLAGBIT)) continue;
        int b = n >> 10, hw = n & 1023;
        __syncthreads();
#pragma unroll
        for (int j = 0; j < 4; ++j)
            zr[(l << 2) + j] = Z[(size_t)((b << 8) + (l << 2) + j) * HWN + hw];
        __syncthreads();
        const float z2v = z2[n];
        float gbest = __builtin_inff();
        int bi = KK;
        for (int kk = 0; kk < 16; ++kk) {
            int k = (kk << 6) + l;
            double dot = 0.0;
            for (int d = 0; d < DD; d += 4) {
                float4 e4 = *reinterpret_cast<const float4*>(&E[(size_t)k * DD + d]);
                dot += (double)e4.x * zr[d]     + (double)e4.y * zr[d + 1]
                     + (double)e4.z * zr[d + 2] + (double)e4.w * zr[d + 3];
            }
            float c = (float)dot;
            float t = __fmul_rn(2.0f, c);
            float gg = __fsub_rn(__fadd_rn(z2v, e2[k]), t);
            if (gg < gbest) { gbest = gg; bi = k; }
        }
#pragma unroll
        for (int off = 32; off > 0; off >>= 1) {
            float og = __shfl_down(gbest, off);
            int oi = __shfl_down(bi, off);
            if (og < gbest || (og == gbest && oi < bi)) { gbest = og; bi = oi; }
        }
        if (l == 0) bestIdx[n] = bi;
    }
}

// -------- outputs: idx, loss (NHWC), z_q (NCHW) --------
__global__ __launch_bounds__(256) void k_out(const float* __restrict__ Z,
                                             const float* __restrict__ E,
                                             const int* __restrict__ bestIdx,
                                             float* __restrict__ out) {
    __shared__ float zc[64][68];
    __shared__ int idxs[64];
    const int th = threadIdx.x;
    const int n0 = blockIdx.x << 6;
    const int b = n0 >> 10;
    const int hw0 = n0 & 1023;

    if (th < 64) {
        int id = bestIdx[n0 + th] & 1023;
        idxs[th] = id;
        out[IDX_OFF + n0 + th] = (float)id;
    }
    __syncthreads();

    for (int dc = 0; dc < 4; ++dc) {
        __syncthreads();
#pragma unroll
        for (int j = 0; j < 16; ++j) {
            int li = (j << 8) + th;
            int dd = li >> 6;
            int r = li & 63;
            zc[r][dd] = Z[(size_t)((b << 8) + (dc << 6) + dd) * HWN + hw0 + r];
        }
        __syncthreads();
#pragma unroll
        for (int j = 0; j < 4; ++j) {
            int i4 = (j << 8) + th;
            int r = i4 >> 4;
            int f = (i4 & 15) << 2;
            float4 e4 = *reinterpret_cast<const float4*>(
                &E[(size_t)idxs[r] * DD + (dc << 6) + f]);
            float4 z4 = *reinterpret_cast<const float4*>(&zc[r][f]);
            float4 o;
            o.x = (e4.x - z4.x) * (e4.x - z4.x);
            o.y = (e4.y - z4.y) * (e4.y - z4.y);
            o.z = (e4.z - z4.z) * (e4.z - z4.z);
            o.w = (e4.w - z4.w) * (e4.w - z4.w);
            *reinterpret_cast<float4*>(
                &out[LOSS_OFF + (size_t)(n0 + r) * DD + (dc << 6) + f]) = o;
        }
#pragma unroll
        for (int j = 0; j < 16; ++j) {
            int li = (j << 8) + th;
            int dd = li >> 6;
            int r = li & 63;
            out[ZQ_OFF + (size_t)((b << 8) + (dc << 6) + dd) * HWN + hw0 + r] =
                E[(size_t)idxs[r] * DD + (dc << 6) + dd];
        }
    }
}

extern "C" void kernel_launch(void* const* d_in, const int* in_sizes, int n_in,
                              void* d_out, int out_size, void* d_ws, size_t ws_size,
                              hipStream_t stream) {
    const float* Z = (const float*)d_in[0];           // [32,256,32,32] f32
    const float* E = (const float*)d_in[1];           // [1024,256] f32
    float* out = (float*)d_out;
    char* ws = (char*)d_ws;
    float* e2 = (float*)ws;
    float* z2 = (float*)(ws + 4096);
    int* bestIdx = (int*)(ws + 135168);

    k_e2<<<KK / 64, 64, 0, stream>>>(E, e2);

    if (ws_size >= WS_NEED) {
        float* part = (float*)(ws + 266240);
        ushort* Eh = (ushort*)(ws + 3411968);
        ushort* El = (ushort*)(ws + 3936256);
        ushort* Zh = (ushort*)(ws + 4460544);
        int* flagCount = (int*)(ws + 38014976);
        int* flagList = (int*)(ws + 38015040);
        k_prepE<<<256, 256, 0, stream>>>(E, Eh, El, flagCount);
        k_prepZ2<<<2048, 256, 0, stream>>>(Z, Zh, z2);
        k_dist_mfma<<<2048, 256, 0, stream>>>(Zh, Eh, El, e2, part);
        k_combine<<<NN / 256, 256, 0, stream>>>(part, bestIdx, flagList, flagCount);
        k_refine3<<<2048, 256, 0, stream>>>(Z, E, e2, z2, bestIdx, flagList, flagCount);
    } else {
        k_z2<<<NN / 256, 256, 0, stream>>>(Z, z2);
        k_dist_f32<<<NN / 64, 256, 0, stream>>>(Z, E, e2, bestIdx);
        k_refine<<<NN / 16, 64, 0, stream>>>(Z, E, e2, z2, bestIdx);
    }

    k_out<<<NN / 64, 256, 0, stream>>>(Z, E, bestIdx, out);
}

// Round 16
// 179.170 us; speedup vs baseline: 1.8342x; 1.1247x over previous
//
#include <hip/hip_runtime.h>

#define DD 256
#define HWN 1024
#define NN 32768
#define KK 1024
#define MARGIN 1e-4f
#define FLAGBIT (1 << 30)

// f32-element offsets into d_out (out_size = 16809984 floats):
#define ZQ_OFF   0          // z_q   [32,256,32,32]
#define IDX_OFF  8388608    // idx   [32768]
#define LOSS_OFF 8421376    // loss  [32,32,32,256] (NHWC)

// ws layout (MFMA path needs WS_NEED bytes; else fp32 fallback):
// [0, 4096)            float e2[1024]
// [4096, 135168)       float z2[32768]
// [135168, 266240)     int   bestIdx[32768]
// [266240, 3411968)    float part[32768][8][3]
// [3411968, 3936256)   ushort Eh[1024][256]   (f16 of 1024*E)
// [3936256, 4460544)   (unused; was El)
// [4460544, 21237760)  ushort Zh[32768][256]  (f16 of Z, [n][d])
// [21237760, 38014976) (unused)
// [38014976, 38015040) int flagCount
// [38015040, 38146112) int flagList[32768]
#define WS_NEED 38146112

typedef __attribute__((ext_vector_type(8))) _Float16 f16x8;
typedef __attribute__((ext_vector_type(4))) float f32x4;

__device__ __forceinline__ ushort f2h(float x) {
    _Float16 h = (_Float16)x;                  // RNE
    return *reinterpret_cast<ushort*>(&h);
}
__device__ __forceinline__ float h2f(ushort u) {
    _Float16 h = *reinterpret_cast<_Float16*>(&u);
    return (float)h;
}

// LDS slot16 index for element (row r, k-group kgi) — bank-spread swizzle.
// Read and stage use the SAME involution (rule: both-sides-or-neither).
__device__ __forceinline__ int swz(int r, int kgi) {
    return (r << 2) + (kgi ^ (r & 3) ^ ((r >> 2) & 3));
}

// ---------------- e2[k]: numpy-exact f32 codebook norms ----------------
__global__ __launch_bounds__(64) void k_e2(const float* __restrict__ E,
                                           float* __restrict__ e2) {
    int k = (blockIdx.x << 6) + threadIdx.x;
    const float* row = E + (size_t)k * DD;
    float half_[2];
#pragma unroll
    for (int h = 0; h < 2; ++h) {
        const float* a = row + (h << 7);
        float r[8];
#pragma unroll
        for (int j = 0; j < 8; ++j) r[j] = __fmul_rn(a[j], a[j]);
        for (int i = 8; i < 128; i += 8) {
#pragma unroll
            for (int j = 0; j < 8; ++j) {
                float x = a[i + j];
                r[j] = __fadd_rn(r[j], __fmul_rn(x, x));
            }
        }
        half_[h] = __fadd_rn(__fadd_rn(__fadd_rn(r[0], r[1]), __fadd_rn(r[2], r[3])),
                             __fadd_rn(__fadd_rn(r[4], r[5]), __fadd_rn(r[6], r[7])));
    }
    e2[k] = __fadd_rn(half_[0], half_[1]);
}

// -- fused: Z transpose tile -> Zh f16 [n][d] + numpy-exact z2 --
__global__ __launch_bounds__(256) void k_prepZ2(const float* __restrict__ Z,
                                                ushort* __restrict__ Zh,
                                                float* __restrict__ z2) {
    __shared__ float zc[16][257];      // 16448 B
    const int g = blockIdx.x;          // 2048 blocks: 16 rows each
    const int b = g >> 6;
    const int hw0 = (g & 63) << 4;
    const int th = threadIdx.x;
    const int n0 = (b << 10) + hw0;

#pragma unroll
    for (int j = 0; j < 16; ++j) {
        int li = (j << 8) + th;        // 0..4095
        int d = li >> 4;
        int hl = li & 15;
        zc[hl][d] = Z[(size_t)((b << 8) + d) * HWN + hw0 + hl];
    }
    __syncthreads();

    // f16 (RNE), [n][d] layout, 32B/thread contiguous
    {
        int r = th >> 4, c = th & 15;
        ushort hs[16];
#pragma unroll
        for (int i = 0; i < 16; ++i) hs[i] = f2h(zc[r][(c << 4) + i]);
        size_t addr = (size_t)(n0 + r) * DD + (c << 4);
        *reinterpret_cast<f16x8*>(&Zh[addr]) = *reinterpret_cast<f16x8*>(&hs[0]);
        *reinterpret_cast<f16x8*>(&Zh[addr + 8]) = *reinterpret_cast<f16x8*>(&hs[8]);
    }

    // z2: numpy pairwise (identical op order to the validated k_z2)
    if (th < 16) {
        const float* rowp = &zc[th][0];
        float half_[2];
#pragma unroll
        for (int h = 0; h < 2; ++h) {
            const float* a = rowp + (h << 7);
            float r[8];
#pragma unroll
            for (int j = 0; j < 8; ++j) r[j] = __fmul_rn(a[j], a[j]);
            for (int i = 8; i < 128; i += 8) {
#pragma unroll
                for (int j = 0; j < 8; ++j) {
                    float x = a[i + j];
                    r[j] = __fadd_rn(r[j], __fmul_rn(x, x));
                }
            }
            half_[h] = __fadd_rn(__fadd_rn(__fadd_rn(r[0], r[1]), __fadd_rn(r[2], r[3])),
                                 __fadd_rn(__fadd_rn(r[4], r[5]), __fadd_rn(r[6], r[7])));
        }
        z2[n0 + th] = __fadd_rn(half_[0], half_[1]);
    }
}

// ---------------- z2 standalone (fallback path only) ----------------
__global__ __launch_bounds__(256) void k_z2(const float* __restrict__ Z,
                                            float* __restrict__ z2) {
    int n = (blockIdx.x << 8) + threadIdx.x;
    int b = n >> 10, hw = n & 1023;
    const float* base = Z + (size_t)(b << 8) * HWN + hw;
    float half_[2];
#pragma unroll
    for (int h = 0; h < 2; ++h) {
        const float* a = base + (size_t)(h << 7) * HWN;
        float r[8];
#pragma unroll
        for (int j = 0; j < 8; ++j) {
            float x = a[(size_t)j * HWN];
            r[j] = __fmul_rn(x, x);
        }
        for (int i = 8; i < 128; i += 8) {
#pragma unroll
            for (int j = 0; j < 8; ++j) {
                float x = a[(size_t)(i + j) * HWN];
                r[j] = __fadd_rn(r[j], __fmul_rn(x, x));
            }
        }
        half_[h] = __fadd_rn(__fadd_rn(__fadd_rn(r[0], r[1]), __fadd_rn(r[2], r[3])),
                             __fadd_rn(__fadd_rn(r[4], r[5]), __fadd_rn(r[6], r[7])));
    }
    z2[n] = __fadd_rn(half_[0], half_[1]);
}

// ------- prep: E -> Eh f16 of 1024*E (+ zero flag counter) -------
// single-term pass-1: el residual (~5e-6 on distance) covered by MARGIN (14 sigma)
__global__ __launch_bounds__(256) void k_prepE(const float* __restrict__ E,
                                               ushort* __restrict__ Eh,
                                               int* __restrict__ flagCount) {
    if (blockIdx.x == 0 && threadIdx.x == 0) *flagCount = 0;
    int i4 = (blockIdx.x << 8) + threadIdx.x;        // 0..65535 float4s
    float4 v = *reinterpret_cast<const float4*>(&E[(size_t)i4 << 2]);
    v.x *= 1024.f; v.y *= 1024.f; v.z *= 1024.f; v.w *= 1024.f;   // exact
    ushort4 h;
    h.x = f2h(v.x); h.y = f2h(v.y); h.z = f2h(v.z); h.w = f2h(v.w);
    *reinterpret_cast<ushort4*>(&Eh[(size_t)i4 << 2]) = h;
}

// --- MFMA distance pass: global_load_lds + swizzle + counted-vmcnt, 1-term f16 ---
__device__ __forceinline__ void stage_kc(const ushort* __restrict__ Zh,
                                         const ushort* __restrict__ Eh,
                                         ushort* ldsbuf, int n0, int c0, int kc,
                                         int wid, int lane) {
#pragma unroll
    for (int is = 0; is < 4; ++is) {
        const int chunk = (wid << 2) + is;   // 0..15 (wave-uniform)
        const int arr = chunk >> 3;          // 0: zh, 1: eh
        const int cb8 = chunk & 7;           // chunk within array
        const int s = (cb8 << 6) + lane;     // slot16 this lane fills
        const int r = s >> 2;
        const int kgi = (s & 3) ^ (r & 3) ^ ((r >> 2) & 3);   // inverse swizzle
        const ushort* g = (arr == 0) ? Zh + (size_t)(n0 + r) * DD
                                     : Eh + (size_t)(c0 + r) * DD;
        g += (kc << 5) + (kgi << 3);
        ushort* l = ldsbuf + arr * 4096 + (cb8 << 9);   // linear dest; HW adds lane*16B
        __builtin_amdgcn_global_load_lds(
            (const __attribute__((address_space(1))) void*)g,
            (__attribute__((address_space(3))) void*)l, 16, 0, 0);
    }
}

__global__ __launch_bounds__(256) void k_dist_mfma(const ushort* __restrict__ Zh,
                                                   const ushort* __restrict__ Eh,
                                                   const float* __restrict__ e2,
                                                   float* __restrict__ part) {
    __shared__ ushort lds[2][2][4096];     // 32768 B: double-buffered {zh, eh}
    __shared__ float red[128][2][3];       //  3072 B  -> 35840 B: 4 blocks/CU

    const int B = blockIdx.x;              // 2048 blocks
    const int xcd = B & 7;
    const int j = B >> 3;                  // 0..255
    const int cb = j & 7;
    const int rb = (xcd << 5) + (j >> 3);
    const int n0 = rb << 7, c0 = cb << 7;
    const int th = threadIdx.x;
    const int wid = th >> 6, lane = th & 63;
    const int wr = wid >> 1, wc = wid & 1;
    const int fr = lane & 15, kgi = lane >> 4;

    f32x4 acc[4][4];
#pragma unroll
    for (int i = 0; i < 4; ++i)
#pragma unroll
        for (int jj = 0; jj < 4; ++jj) acc[i][jj] = (f32x4){0.f, 0.f, 0.f, 0.f};

    stage_kc(Zh, Eh, &lds[0][0][0], n0, c0, 0, wid, lane);

    for (int kc = 0; kc < 8; ++kc) {
        // barrier A: previous iter's LDS reads done before overwriting that buffer
        __builtin_amdgcn_s_barrier();
        if (kc < 7) {
            stage_kc(Zh, Eh, &lds[(kc + 1) & 1][0][0], n0, c0, kc + 1, wid, lane);
            // wait only MY stage(kc) loads (4 newer stay in flight across barrier)
            asm volatile("s_waitcnt vmcnt(4)" ::: "memory");
        } else {
            asm volatile("s_waitcnt vmcnt(0)" ::: "memory");
        }
        // barrier B: ALL waves' stage(kc) loads have landed
        __builtin_amdgcn_s_barrier();

        const ushort* zb  = &lds[kc & 1][0][0];
        const ushort* ebh = &lds[kc & 1][1][0];
        f16x8 za[4], ea[4];
#pragma unroll
        for (int mi = 0; mi < 4; ++mi) {
            int r = (wr << 6) + (mi << 4) + fr;
            za[mi] = *reinterpret_cast<const f16x8*>(zb + (swz(r, kgi) << 3));
        }
#pragma unroll
        for (int ni = 0; ni < 4; ++ni) {
            int c = (wc << 6) + (ni << 4) + fr;
            ea[ni] = *reinterpret_cast<const f16x8*>(ebh + (swz(c, kgi) << 3));
        }
        __builtin_amdgcn_s_setprio(1);
#pragma unroll
        for (int mi = 0; mi < 4; ++mi)
#pragma unroll
            for (int ni = 0; ni < 4; ++ni)
                acc[mi][ni] = __builtin_amdgcn_mfma_f32_16x16x32_f16(za[mi], ea[ni], acc[mi][ni], 0, 0, 0);
        __builtin_amdgcn_s_setprio(0);
    }

    float e2v[4];
#pragma unroll
    for (int ni = 0; ni < 4; ++ni) e2v[ni] = e2[c0 + (wc << 6) + (ni << 4) + fr];

#pragma unroll
    for (int mi = 0; mi < 4; ++mi) {
#pragma unroll
        for (int jj = 0; jj < 4; ++jj) {
            float m1 = __builtin_inff(), m2 = __builtin_inff(), bi = 3.4e38f;
#pragma unroll
            for (int ni = 0; ni < 4; ++ni) {
                float s = fmaf(-0x1p-9f, acc[mi][ni][jj], e2v[ni]);  // -2*dot, undo x1024
                float c = (float)(c0 + (wc << 6) + (ni << 4) + fr);
                if (s < m1)      { m2 = m1; m1 = s; bi = c; }
                else if (s < m2) { m2 = s; }
            }
#pragma unroll
            for (int m = 1; m <= 8; m <<= 1) {
                float om1 = __shfl_xor(m1, m);
                float om2 = __shfl_xor(m2, m);
                float obi = __shfl_xor(bi, m);
                if (om1 < m1)       { m2 = fminf(m1, om2); m1 = om1; bi = obi; }
                else if (om1 == m1) { bi = fminf(bi, obi); m2 = m1; }
                else                { m2 = fminf(m2, om1); }
            }
            if (fr == 0) {
                int row = (wr << 6) + (mi << 4) + (kgi << 2) + jj;
                red[row][wc][0] = m1; red[row][wc][1] = m2; red[row][wc][2] = bi;
            }
        }
    }
    __syncthreads();
    if (th < 128) {
        float M1 = red[th][0][0], M2 = red[th][0][1], I = red[th][0][2];
        float v1 = red[th][1][0], v2 = red[th][1][1], vi = red[th][1][2];
        if (v1 < M1)       { M2 = fminf(M1, v2); M1 = v1; I = vi; }
        else if (v1 == M1) { I = fminf(I, vi); M2 = M1; }
        else               { M2 = fminf(M2, v1); }
        size_t p = ((size_t)(n0 + th) * 8 + cb) * 3;
        part[p] = M1; part[p + 1] = M2; part[p + 2] = I;
    }
}

// ------- combine 8 code-slices -> bestIdx + compacted near-tie list -------
__global__ __launch_bounds__(256) void k_combine(const float* __restrict__ part,
                                                 int* __restrict__ bestIdx,
                                                 int* __restrict__ flagList,
                                                 int* __restrict__ flagCount) {
    int n = (blockIdx.x << 8) + threadIdx.x;
    const float* p = part + (size_t)n * 24;
    float M1 = __builtin_inff(), M2 = __builtin_inff(), I = 3.4e38f;
    for (int c = 0; c < 8; ++c) {
        float v1 = p[c * 3], v2 = p[c * 3 + 1], vi = p[c * 3 + 2];
        if (v1 < M1)       { M2 = fminf(M1, v2); M1 = v1; I = vi; }
        else if (v1 == M1) { I = fminf(I, vi); M2 = M1; }
        else               { M2 = fminf(M2, v1); }
    }
    bestIdx[n] = (int)I;
    if (M2 - M1 < MARGIN) {
        int pos = atomicAdd(flagCount, 1);
        flagList[pos] = n;
    }
}

// ---- np-f32-grid re-argmin: 1 row/block, 16 code-groups x 16 lanes, no E staging ----
__global__ __launch_bounds__(256) void k_refine3(const float* __restrict__ Z,
                                                 const float* __restrict__ E,
                                                 const float* __restrict__ e2,
                                                 const float* __restrict__ z2,
                                                 int* __restrict__ bestIdx,
                                                 const int* __restrict__ flagList,
                                                 const int* __restrict__ flagCount) {
    __shared__ float zsh[DD];
    __shared__ float gbv[16];
    __shared__ int gbi[16];
    const int th = threadIdx.x;
    const int g = th >> 4;             // code group 0..15
    const int l = th & 15;             // lane in group
    const int cnt = *flagCount;

    for (int i = blockIdx.x; i < cnt; i += (int)gridDim.x) {
        const int n = flagList[i];
        const int b = n >> 10, hw = n & 1023;
        __syncthreads();               // protect zsh/gbv/gbi from previous row
        if (th < DD) zsh[th] = Z[(size_t)((b << 8) + th) * HWN + hw];
        __syncthreads();
        float zr[16];
#pragma unroll
        for (int jq = 0; jq < 16; ++jq) zr[jq] = zsh[(l << 4) + jq];
        const float z2v = z2[n];
        float gbest = __builtin_inff();
        int bi = 0;

        for (int it = 0; it < 64; ++it) {
            const int c = (it << 4) + g;              // ascending per group
            const float* er = &E[(size_t)c * DD + (l << 4)];
            float4 a0 = *reinterpret_cast<const float4*>(er);
            float4 a1 = *reinterpret_cast<const float4*>(er + 4);
            float4 a2 = *reinterpret_cast<const float4*>(er + 8);
            float4 a3 = *reinterpret_cast<const float4*>(er + 12);
            double s0 = (double)a0.x * zr[0]  + (double)a0.y * zr[1]
                      + (double)a0.z * zr[2]  + (double)a0.w * zr[3];
            double s1 = (double)a1.x * zr[4]  + (double)a1.y * zr[5]
                      + (double)a1.z * zr[6]  + (double)a1.w * zr[7];
            double s2 = (double)a2.x * zr[8]  + (double)a2.y * zr[9]
                      + (double)a2.z * zr[10] + (double)a2.w * zr[11];
            double s3 = (double)a3.x * zr[12] + (double)a3.y * zr[13]
                      + (double)a3.z * zr[14] + (double)a3.w * zr[15];
            double dot = (s0 + s1) + (s2 + s3);
#pragma unroll
            for (int m = 1; m <= 8; m <<= 1) dot += __shfl_xor(dot, m);  // 16-lane sum
            if (l == 0) {
                float cc = (float)dot;
                float t2 = __fmul_rn(2.0f, cc);
                float gg = __fsub_rn(__fadd_rn(z2v, e2[c]), t2);
                if (gg < gbest) { gbest = gg; bi = c; }   // lowest c wins ties
            }
        }
        if (l == 0) { gbv[g] = gbest; gbi[g] = bi; }
        __syncthreads();
        if (th == 0) {
            float best = gbv[0]; int bbi = gbi[0];
            for (int q = 1; q < 16; ++q) {
                float v = gbv[q]; int vi = gbi[q];
                if (v < best || (v == best && vi < bbi)) { best = v; bbi = vi; }
            }
            bestIdx[n] = bbi;
        }
    }
}

// ======== fp32 fallback distance pass (used if ws too small) ========
#define UPD(m1, m2, i1, s, k)                            \
    do {                                                 \
        if ((s) < (m1)) { m2 = m1; m1 = (s); i1 = (k); } \
        else if ((s) < (m2)) { m2 = (s); }               \
    } while (0)

#define FMAJ(j, EV, C)                                   \
    acc[0][j] = fmaf(z4.x, EV.C, acc[0][j]);             \
    acc[1][j] = fmaf(z4.y, EV.C, acc[1][j]);             \
    acc[2][j] = fmaf(z4.z, EV.C, acc[2][j]);             \
    acc[3][j] = fmaf(z4.w, EV.C, acc[3][j]);

#define UROUND(u, C)                                                          \
    {                                                                         \
        float4 z4 = *reinterpret_cast<const float4*>(&zs[dq + u][ty4]);       \
        FMAJ(0, e0, C) FMAJ(1, e1, C) FMAJ(2, e2v, C) FMAJ(3, e3, C)          \
        FMAJ(4, e4, C) FMAJ(5, e5, C) FMAJ(6, e6, C) FMAJ(7, e7, C)           \
    }

__global__ __launch_bounds__(256, 3) void k_dist_f32(const float* __restrict__ Z,
                                                     const float* __restrict__ E,
                                                     const float* __restrict__ e2,
                                                     int* __restrict__ bestIdx) {
    __shared__ float zs[64][68];
    __shared__ float es[128][68];
    const int th = threadIdx.x;
    const int n0 = blockIdx.x << 6;
    const int b = n0 >> 10;
    const int hw0 = n0 & 1023;
    const int tx = th & 15;
    const int ty = th >> 4;
    const int ty4 = ty << 2;
    float m1[4], m2[4];
    int idx[4];
#pragma unroll
    for (int i = 0; i < 4; ++i) { m1[i] = __builtin_inff(); m2[i] = __builtin_inff(); idx[i] = 0; }
    for (int ct = 0; ct < 8; ++ct) {
        float acc[4][8];
#pragma unroll
        for (int i = 0; i < 4; ++i)
#pragma unroll
            for (int j = 0; j < 8; ++j) acc[i][j] = 0.f;
        for (int dc = 0; dc < 4; ++dc) {
            __syncthreads();
#pragma unroll
            for (int j = 0; j < 4; ++j) {
                int i4 = (j << 8) + th;
                int dd = i4 >> 4;
                int rr = (i4 & 15) << 2;
                *reinterpret_cast<float4*>(&zs[dd][rr]) =
                    *reinterpret_cast<const float4*>(
                        &Z[(size_t)((b << 8) + (dc << 6) + dd) * HWN + hw0 + rr]);
            }
#pragma unroll
            for (int j = 0; j < 8; ++j) {
                int i4 = (j << 8) + th;
                int c = i4 >> 4;
                int d4 = (i4 & 15) << 2;
                *reinterpret_cast<float4*>(&es[c][d4]) =
                    *reinterpret_cast<const float4*>(
                        &E[(size_t)((ct << 7) + c) * DD + (dc << 6) + d4]);
            }
            __syncthreads();
#pragma unroll
            for (int dq = 0; dq < 64; dq += 4) {
                float4 e0 = *reinterpret_cast<const float4*>(&es[tx][dq]);
                float4 e1 = *reinterpret_cast<const float4*>(&es[tx + 16][dq]);
                float4 e2v = *reinterpret_cast<const float4*>(&es[tx + 32][dq]);
                float4 e3 = *reinterpret_cast<const float4*>(&es[tx + 48][dq]);
                float4 e4 = *reinterpret_cast<const float4*>(&es[tx + 64][dq]);
                float4 e5 = *reinterpret_cast<const float4*>(&es[tx + 80][dq]);
                float4 e6 = *reinterpret_cast<const float4*>(&es[tx + 96][dq]);
                float4 e7 = *reinterpret_cast<const float4*>(&es[tx + 112][dq]);
                UROUND(0, x)
                UROUND(1, y)
                UROUND(2, z)
                UROUND(3, w)
            }
        }
#pragma unroll
        for (int j = 0; j < 8; ++j) {
            int c = (ct << 7) + tx + (j << 4);
            float en = e2[c];
#pragma unroll
            for (int i = 0; i < 4; ++i) {
                float s = fmaf(-2.f, acc[i][j], en);
                UPD(m1[i], m2[i], idx[i], s, c);
            }
        }
    }
    __syncthreads();
    float* red = &es[0][0];
#pragma unroll
    for (int i = 0; i < 4; ++i) {
        int r = ty4 + i;
        int base = ((r << 4) + tx) * 3;
        red[base] = m1[i]; red[base + 1] = m2[i]; red[base + 2] = (float)idx[i];
    }
    __syncthreads();
    if (th < 64) {
        float M1 = __builtin_inff(), M2 = __builtin_inff(), I = 3.4e38f;
        for (int t = 0; t < 16; ++t) {
            int base = ((th << 4) + t) * 3;
            float v1 = red[base], v2 = red[base + 1], vi = red[base + 2];
            if (v1 < M1)       { M2 = fminf(M1, v2); M1 = v1; I = vi; }
            else if (v1 == M1) { I = fminf(I, vi); M2 = fminf(M2, v1); M2 = fminf(M2, v2); }
            else               { M2 = fminf(M2, v1); }
        }
        int id = (int)I;
        bestIdx[n0 + th] = (M2 - M1 < MARGIN) ? (id | FLAGBIT) : id;
    }
}

// -------- fallback-path refine (FLAGBIT scan, unchanged semantics) --------
__global__ __launch_bounds__(64) void k_refine(const float* __restrict__ Z,
                                               const float* __restrict__ E,
                                               const float* __restrict__ e2,
                                               const float* __restrict__ z2,
                                               int* __restrict__ bestIdx) {
    __shared__ float zr[DD];
    const int l = threadIdx.x;
    for (int i = 0; i < 16; ++i) {
        int n = (blockIdx.x << 4) + i;
        if (!(bestIdx[n] & FLAGBIT)) continue;
        int b = n >> 10, hw = n & 1023;
        __syncthreads();
#pragma unroll
        for (int j = 0; j < 4; ++j)
            zr[(l << 2) + j] = Z[(size_t)((b << 8) + (l << 2) + j) * HWN + hw];
        __syncthreads();
        const float z2v = z2[n];
        float gbest = __builtin_inff();
        int bi = KK;
        for (int kk = 0; kk < 16; ++kk) {
            int k = (kk << 6) + l;
            double dot = 0.0;
            for (int d = 0; d < DD; d += 4) {
                float4 e4 = *reinterpret_cast<const float4*>(&E[(size_t)k * DD + d]);
                dot += (double)e4.x * zr[d]     + (double)e4.y * zr[d + 1]
                     + (double)e4.z * zr[d + 2] + (double)e4.w * zr[d + 3];
            }
            float c = (float)dot;
            float t = __fmul_rn(2.0f, c);
            float gg = __fsub_rn(__fadd_rn(z2v, e2[k]), t);
            if (gg < gbest) { gbest = gg; bi = k; }
        }
#pragma unroll
        for (int off = 32; off > 0; off >>= 1) {
            float og = __shfl_down(gbest, off);
            int oi = __shfl_down(bi, off);
            if (og < gbest || (og == gbest && oi < bi)) { gbest = og; bi = oi; }
        }
        if (l == 0) bestIdx[n] = bi;
    }
}

// -------- outputs: idx, loss (NHWC), z_q (NCHW) --------
__global__ __launch_bounds__(256) void k_out(const float* __restrict__ Z,
                                             const float* __restrict__ E,
                                             const int* __restrict__ bestIdx,
                                             float* __restrict__ out) {
    __shared__ float zc[64][68];
    __shared__ int idxs[64];
    const int th = threadIdx.x;
    const int n0 = blockIdx.x << 6;
    const int b = n0 >> 10;
    const int hw0 = n0 & 1023;

    if (th < 64) {
        int id = bestIdx[n0 + th] & 1023;
        idxs[th] = id;
        out[IDX_OFF + n0 + th] = (float)id;
    }
    __syncthreads();

    for (int dc = 0; dc < 4; ++dc) {
        __syncthreads();
#pragma unroll
        for (int j = 0; j < 16; ++j) {
            int li = (j << 8) + th;
            int dd = li >> 6;
            int r = li & 63;
            zc[r][dd] = Z[(size_t)((b << 8) + (dc << 6) + dd) * HWN + hw0 + r];
        }
        __syncthreads();
#pragma unroll
        for (int j = 0; j < 4; ++j) {
            int i4 = (j << 8) + th;
            int r = i4 >> 4;
            int f = (i4 & 15) << 2;
            float4 e4 = *reinterpret_cast<const float4*>(
                &E[(size_t)idxs[r] * DD + (dc << 6) + f]);
            float4 z4 = *reinterpret_cast<const float4*>(&zc[r][f]);
            float4 o;
            o.x = (e4.x - z4.x) * (e4.x - z4.x);
            o.y = (e4.y - z4.y) * (e4.y - z4.y);
            o.z = (e4.z - z4.z) * (e4.z - z4.z);
            o.w = (e4.w - z4.w) * (e4.w - z4.w);
            *reinterpret_cast<float4*>(
                &out[LOSS_OFF + (size_t)(n0 + r) * DD + (dc << 6) + f]) = o;
        }
#pragma unroll
        for (int j = 0; j < 16; ++j) {
            int li = (j << 8) + th;
            int dd = li >> 6;
            int r = li & 63;
            out[ZQ_OFF + (size_t)((b << 8) + (dc << 6) + dd) * HWN + hw0 + r] =
                E[(size_t)idxs[r] * DD + (dc << 6) + dd];
        }
    }
}

extern "C" void kernel_launch(void* const* d_in, const int* in_sizes, int n_in,
                              void* d_out, int out_size, void* d_ws, size_t ws_size,
                              hipStream_t stream) {
    const float* Z = (const float*)d_in[0];           // [32,256,32,32] f32
    const float* E = (const float*)d_in[1];           // [1024,256] f32
    float* out = (float*)d_out;
    char* ws = (char*)d_ws;
    float* e2 = (float*)ws;
    float* z2 = (float*)(ws + 4096);
    int* bestIdx = (int*)(ws + 135168);

    k_e2<<<KK / 64, 64, 0, stream>>>(E, e2);

    if (ws_size >= WS_NEED) {
        float* part = (float*)(ws + 266240);
        ushort* Eh = (ushort*)(ws + 3411968);
        ushort* Zh = (ushort*)(ws + 4460544);
        int* flagCount = (int*)(ws + 38014976);
        int* flagList = (int*)(ws + 38015040);
        k_prepE<<<256, 256, 0, stream>>>(E, Eh, flagCount);
        k_prepZ2<<<2048, 256, 0, stream>>>(Z, Zh, z2);
        k_dist_mfma<<<2048, 256, 0, stream>>>(Zh, Eh, e2, part);
        k_combine<<<NN / 256, 256, 0, stream>>>(part, bestIdx, flagList, flagCount);
        k_refine3<<<2048, 256, 0, stream>>>(Z, E, e2, z2, bestIdx, flagList, flagCount);
    } else {
        k_z2<<<NN / 256, 256, 0, stream>>>(Z, z2);
        k_dist_f32<<<NN / 64, 256, 0, stream>>>(Z, E, e2, bestIdx);
        k_refine<<<NN / 16, 64, 0, stream>>>(Z, E, e2, z2, bestIdx);
    }

    k_out<<<NN / 64, 256, 0, stream>>>(Z, E, bestIdx, out);
}